// Round 13
// baseline (251.752 us; speedup 1.0000x reference)
//
#include <hip/hip_runtime.h>
#include <hip/hip_fp16.h>
#include <math.h>

#define BKT_SHIFT 8
#define BKT_NODES 256
#define HROWS 64

// ---- pass 1: per-bucket histogram (int4-vectorized dst read) ----
__global__ __launch_bounds__(256) void k_hist(const int* __restrict__ dst,
                                              int* __restrict__ bcnt, int E, int NB) {
    __shared__ int lh[512];
    for (int i = threadIdx.x; i < NB; i += 256) lh[i] = 0;
    __syncthreads();
    int base = blockIdx.x * 4096;
    if (base + 4096 <= E) {
        const int4* d4 = (const int4*)(dst + base);
#pragma unroll
        for (int k = 0; k < 4; ++k) {
            int4 v = d4[k * 256 + threadIdx.x];
            atomicAdd(&lh[v.x >> BKT_SHIFT], 1);
            atomicAdd(&lh[v.y >> BKT_SHIFT], 1);
            atomicAdd(&lh[v.z >> BKT_SHIFT], 1);
            atomicAdd(&lh[v.w >> BKT_SHIFT], 1);
        }
    } else {
        for (int k = 0; k < 16; ++k) {
            int i = base + k * 256 + threadIdx.x;
            if (i < E) atomicAdd(&lh[dst[i] >> BKT_SHIFT], 1);
        }
    }
    __syncthreads();
    for (int i = threadIdx.x; i < NB; i += 256)
        if (lh[i]) atomicAdd(&bcnt[i], lh[i]);
}

// ---- exclusive scan over NB buckets (single block) ----
__global__ __launch_bounds__(512) void k_bscan(const int* __restrict__ bc,
                                               int* __restrict__ boff,
                                               int* __restrict__ bcur, int NB, int E) {
    __shared__ int s[512];
    __shared__ int carry;
    if (threadIdx.x == 0) carry = 0;
    __syncthreads();
    for (int base = 0; base < NB; base += 512) {
        int i = base + threadIdx.x;
        int v = (i < NB) ? bc[i] : 0;
        s[threadIdx.x] = v;
        __syncthreads();
        for (int off = 1; off < 512; off <<= 1) {
            int t = (threadIdx.x >= off) ? s[threadIdx.x - off] : 0;
            __syncthreads();
            s[threadIdx.x] += t;
            __syncthreads();
        }
        if (i < NB) {
            int ex = carry + s[threadIdx.x] - v;
            boff[i] = ex;
            bcur[i] = ex;
        }
        __syncthreads();
        if (threadIdx.x == 0) carry += s[511];
        __syncthreads();
    }
    if (threadIdx.x == 0) boff[NB] = E;
}

// ---- pass 2: partition edges; record = (d&255)<<24 | src ----
// 2048 edges/block, no dstash (dst re-read hits L1/L2), 2KB LDS -> high occupancy
__global__ __launch_bounds__(256) void k_part(const int* __restrict__ src,
                                              const int* __restrict__ dst,
                                              int* __restrict__ bcur,
                                              int* __restrict__ ebuf, int E, int NB) {
    __shared__ int lh[512];
    for (int i = threadIdx.x; i < NB; i += 256) lh[i] = 0;
    __syncthreads();
    int base = blockIdx.x * 2048;
    if (base + 2048 <= E) {
        const int4* d4 = (const int4*)(dst + base);
#pragma unroll
        for (int k = 0; k < 2; ++k) {
            int4 v = d4[k * 256 + threadIdx.x];
            atomicAdd(&lh[v.x >> BKT_SHIFT], 1);
            atomicAdd(&lh[v.y >> BKT_SHIFT], 1);
            atomicAdd(&lh[v.z >> BKT_SHIFT], 1);
            atomicAdd(&lh[v.w >> BKT_SHIFT], 1);
        }
    } else {
        for (int k = 0; k < 8; ++k) {
            int i = base + k * 256 + threadIdx.x;
            if (i < E) atomicAdd(&lh[dst[i] >> BKT_SHIFT], 1);
        }
    }
    __syncthreads();
    for (int t = threadIdx.x; t < NB; t += 256) {
        int c = lh[t];
        lh[t] = c ? atomicAdd(&bcur[t], c) : 0;
    }
    __syncthreads();
    if (base + 2048 <= E) {
        const int4* d4 = (const int4*)(dst + base);
        const int4* s4 = (const int4*)(src + base);
#pragma unroll
        for (int k = 0; k < 2; ++k) {
            int4 dv = d4[k * 256 + threadIdx.x];
            int4 sv = s4[k * 256 + threadIdx.x];
            int p;
            p = atomicAdd(&lh[dv.x >> BKT_SHIFT], 1); ebuf[p] = ((dv.x & 255) << 24) | sv.x;
            p = atomicAdd(&lh[dv.y >> BKT_SHIFT], 1); ebuf[p] = ((dv.y & 255) << 24) | sv.y;
            p = atomicAdd(&lh[dv.z >> BKT_SHIFT], 1); ebuf[p] = ((dv.z & 255) << 24) | sv.z;
            p = atomicAdd(&lh[dv.w >> BKT_SHIFT], 1); ebuf[p] = ((dv.w & 255) << 24) | sv.w;
        }
    } else {
        for (int k = 0; k < 8; ++k) {
            int i = base + k * 256 + threadIdx.x;
            if (i < E) {
                int d = dst[i];
                int p = atomicAdd(&lh[d >> BKT_SHIFT], 1);
                ebuf[p] = ((d & 255) << 24) | src[i];
            }
        }
    }
}

// ---- pass 3: per-bucket counting sort -> csr (masked src), rowstart, dinv ----
__global__ __launch_bounds__(256) void k_lsort(const int* __restrict__ boff,
                                               const int* __restrict__ ebuf,
                                               int* __restrict__ rowstart,
                                               float* __restrict__ dinv,
                                               int* __restrict__ csr, int n, int NB) {
    __shared__ int off[256];
    __shared__ int cnt[256];
    int b = blockIdx.x;
    int start = boff[b], end = boff[b + 1];
    cnt[threadIdx.x] = 0;
    __syncthreads();
    for (int i = start + threadIdx.x; i < end; i += 256)
        atomicAdd(&cnt[((unsigned)ebuf[i]) >> 24], 1);
    __syncthreads();
    int v = cnt[threadIdx.x];
    off[threadIdx.x] = v;
    __syncthreads();
    for (int o = 1; o < 256; o <<= 1) {
        int t = (threadIdx.x >= o) ? off[threadIdx.x - o] : 0;
        __syncthreads();
        off[threadIdx.x] += t;
        __syncthreads();
    }
    int excl = off[threadIdx.x] - v;
    int node = (b << BKT_SHIFT) + threadIdx.x;
    if (node < n) {
        rowstart[node] = start + excl;
        dinv[node] = rsqrtf((float)v + 1.0f);  // +1 = self-loop
    }
    __syncthreads();
    off[threadIdx.x] = excl;  // reuse as cursor
    __syncthreads();
    for (int i = start + threadIdx.x; i < end; i += 256) {
        int rec = ebuf[i];
        int d = ((unsigned)rec) >> 24;
        int pos = atomicAdd(&off[d], 1);
        csr[start + pos] = rec & 0xFFFFFF;
    }
    if (b == NB - 1 && threadIdx.x == 0) rowstart[n] = end;
}

// ---- hx = fp16(x * dinv), [N][8] ----
__global__ __launch_bounds__(256) void k_hx(const float* __restrict__ x,
                                            const float* __restrict__ dinv,
                                            __half2* __restrict__ hx, int n4) {
    int t = blockIdx.x * 256 + threadIdx.x;
    if (t >= n4) return;
    float2 v = ((const float2*)x)[t];
    float dv = dinv[t >> 2];
    hx[t] = __floats2half2_rn(v.x * dv, v.y * dv);
}

// ---- fused layer-1: aggregate hx (8 feats) then @W1+bias+ELU ----
__global__ __launch_bounds__(256) void k_agg1f(const int* __restrict__ rs, const int* __restrict__ csr,
                                               const float* __restrict__ dinv, const __half2* __restrict__ hx,
                                               const float* __restrict__ W1, const float* __restrict__ bias,
                                               float* __restrict__ g, int n) {
    __shared__ float w[512];
    for (int i = threadIdx.x; i < 512; i += 256) w[i] = W1[i];
    __syncthreads();
    int wid = (blockIdx.x * 256 + threadIdx.x) >> 6;
    if (wid >= n) return;
    int lane = threadIdx.x & 63;
    int sub = lane >> 2;        // 0..15 edge subset
    int jp = lane & 3;          // half2 index
    int start = rs[wid], end = rs[wid + 1];
    float ax = 0.f, ay = 0.f;
    int i = start + sub;
    for (; i + 16 < end; i += 32) {
        int s0 = csr[i], s1 = csr[i + 16];
        float2 f0 = __half22float2(hx[((size_t)s0 << 2) + jp]);
        float2 f1 = __half22float2(hx[((size_t)s1 << 2) + jp]);
        ax += f0.x + f1.x;
        ay += f0.y + f1.y;
    }
    for (; i < end; i += 16) {
        float2 f = __half22float2(hx[((size_t)csr[i] << 2) + jp]);
        ax += f.x; ay += f.y;
    }
    if (sub == 0) {  // self-loop row
        float2 f = __half22float2(hx[((size_t)wid << 2) + jp]);
        ax += f.x; ay += f.y;
    }
#pragma unroll
    for (int m = 4; m < 64; m <<= 1) {
        ax += __shfl_xor(ax, m);
        ay += __shfl_xor(ay, m);
    }
    float dv = dinv[wid];
    float s = 0.f;
#pragma unroll
    for (int kp = 0; kp < 4; ++kp) {
        float a = __shfl(ax, kp);
        float b = __shfl(ay, kp);
        s += a * w[(2 * kp) * 64 + lane] + b * w[(2 * kp + 1) * 64 + lane];
    }
    float v = dv * s + bias[lane];
    g[(size_t)wid * 64 + lane] = v > 0.f ? v : expm1f(v);
}

// ---- layer-2 aggregation: 4 nodes/wave, 16 lanes/node, unroll 8, no shuffles ----
__global__ __launch_bounds__(256) void k_aggr32x(const int* __restrict__ rs, const int* __restrict__ csr,
                                                 const float* __restrict__ dinv, const __half* __restrict__ hw,
                                                 const float* __restrict__ bias, float* __restrict__ g, int n) {
    int wid = (blockIdx.x * 256 + threadIdx.x) >> 4;
    if (wid >= n) return;
    int j = threadIdx.x & 15;           // feature pair (feats 2j, 2j+1)
    int start = rs[wid], end = rs[wid + 1];
    const __half2* hp = (const __half2*)hw;
    float ax = 0.f, ay = 0.f;
    int i = start;
    for (; i + 8 <= end; i += 8) {
        int s0 = csr[i],     s1 = csr[i + 1], s2 = csr[i + 2], s3 = csr[i + 3];
        int s4 = csr[i + 4], s5 = csr[i + 5], s6 = csr[i + 6], s7 = csr[i + 7];
        float2 f0 = __half22float2(hp[((size_t)s0 << 4) + j]);
        float2 f1 = __half22float2(hp[((size_t)s1 << 4) + j]);
        float2 f2 = __half22float2(hp[((size_t)s2 << 4) + j]);
        float2 f3 = __half22float2(hp[((size_t)s3 << 4) + j]);
        float2 f4 = __half22float2(hp[((size_t)s4 << 4) + j]);
        float2 f5 = __half22float2(hp[((size_t)s5 << 4) + j]);
        float2 f6 = __half22float2(hp[((size_t)s6 << 4) + j]);
        float2 f7 = __half22float2(hp[((size_t)s7 << 4) + j]);
        ax += f0.x + f1.x + f2.x + f3.x + f4.x + f5.x + f6.x + f7.x;
        ay += f0.y + f1.y + f2.y + f3.y + f4.y + f5.y + f6.y + f7.y;
    }
    for (; i < end; ++i) {
        int s = csr[i];
        float2 f = __half22float2(hp[((size_t)s << 4) + j]);
        ax += f.x; ay += f.y;
    }
    float dv = dinv[wid];
    float2 fs = __half22float2(hp[((size_t)wid << 4) + j]);
    float2 bb = ((const float2*)bias)[j];
    float vx = dv * (ax + fs.x) + bb.x;
    float vy = dv * (ay + fs.y) + bb.y;
    float2 r;
    r.x = vx > 0.f ? vx : expm1f(vx);
    r.y = vy > 0.f ? vy : expm1f(vy);
    ((float2*)(g + ((size_t)wid << 5)))[j] = r;
}

// ---- hw2 = fp16((g1 @ W2) * dinv)  (64 -> 32), single plane, plain loads ----
__global__ __launch_bounds__(256) void k_gemm2(const float* __restrict__ g1, const float* __restrict__ W2,
                                               const float* __restrict__ dinv, __half* __restrict__ hw2, int n) {
    __shared__ float w[2048];
    __shared__ float xs[512];
    for (int i = threadIdx.x; i < 2048; i += 256) w[i] = W2[i];
    int nb = blockIdx.x * 8;
    for (int i = threadIdx.x; i < 512; i += 256) {
        int r = i >> 6, c = i & 63;
        int node = nb + r;
        xs[i] = (node < n) ? g1[(size_t)node * 64 + c] : 0.f;
    }
    __syncthreads();
    int node = nb + (threadIdx.x >> 5);
    int j = threadIdx.x & 31;
    if (node >= n) return;
    const float* xr = &xs[(threadIdx.x >> 5) << 6];
    float s = 0.f;
#pragma unroll
    for (int k = 0; k < 64; ++k) s += xr[k] * w[k * 32 + j];
    hw2[(size_t)node * 32 + j] = __float2half_rn(s * dinv[node]);
}

// ---- cooperative head: conv1d(32->16,k=3)+relu+fc(16->22), 64 rows/block, float4 ----
__global__ __launch_bounds__(256) void k_head(const float* __restrict__ g2, const float* __restrict__ cw,
                                              const float* __restrict__ cb, const float* __restrict__ fw,
                                              const float* __restrict__ fb, float* __restrict__ out,
                                              int nrows) {
    __shared__ float tile[(HROWS + 2) * 36];
    __shared__ float scwT[96 * 16];
    __shared__ float ytile[HROWS * 20];
    __shared__ float sfwT[22 * 16];
    __shared__ float scb[16], sfb[22];
    int base = blockIdx.x * HROWS;
    int rcnt = nrows - base; if (rcnt > HROWS) rcnt = HROWS;
    for (int i = threadIdx.x; i < 1536; i += 256) {
        int co = i / 96, rem = i - co * 96;
        scwT[rem * 16 + co] = cw[i];
    }
    for (int i = threadIdx.x; i < 352; i += 256) {
        int co = i / 22, col = i - co * 22;
        sfwT[col * 16 + co] = fw[i];
    }
    if (threadIdx.x < 16) scb[threadIdx.x] = cb[threadIdx.x];
    if (threadIdx.x < 22) sfb[threadIdx.x] = fb[threadIdx.x];
    int nload4 = (rcnt + 2) * 8;
    for (int i = threadIdx.x; i < nload4; i += 256) {
        int r = i >> 3, c4 = i & 7;
        float4 v = *(const float4*)(g2 + (size_t)(base + r) * 32 + c4 * 4);
        *(float4*)&tile[r * 36 + c4 * 4] = v;
    }
    __syncthreads();
    int r = threadIdx.x >> 2;
    int c0 = threadIdx.x & 3;
    if (r < rcnt) {
        float4 acc = { scb[c0 * 4], scb[c0 * 4 + 1], scb[c0 * 4 + 2], scb[c0 * 4 + 3] };
#pragma unroll
        for (int k = 0; k < 3; ++k) {
            const float* tr = &tile[(r + k) * 36];
#pragma unroll
            for (int ci4 = 0; ci4 < 8; ++ci4) {
                float4 xv = *(const float4*)&tr[ci4 * 4];
#pragma unroll
                for (int q = 0; q < 4; ++q) {
                    int ci = ci4 * 4 + q;
                    float4 wv = *(const float4*)&scwT[(ci * 3 + k) * 16 + c0 * 4];
                    float xq = q == 0 ? xv.x : q == 1 ? xv.y : q == 2 ? xv.z : xv.w;
                    acc.x += xq * wv.x;
                    acc.y += xq * wv.y;
                    acc.z += xq * wv.z;
                    acc.w += xq * wv.w;
                }
            }
        }
        float4 yv;
        yv.x = acc.x > 0.f ? acc.x : 0.f;
        yv.y = acc.y > 0.f ? acc.y : 0.f;
        yv.z = acc.z > 0.f ? acc.z : 0.f;
        yv.w = acc.w > 0.f ? acc.w : 0.f;
        *(float4*)&ytile[r * 20 + c0 * 4] = yv;
    }
    __syncthreads();
    int items = rcnt * 22;
    for (int it = threadIdx.x; it < items; it += 256) {
        int row = it / 22, col = it - row * 22;
        const float* yr = &ytile[row * 20];
        const float* wc = &sfwT[col * 16];
        float s = sfb[col];
#pragma unroll
        for (int co4 = 0; co4 < 4; ++co4) {
            float4 yv = *(const float4*)&yr[co4 * 4];
            float4 wv = *(const float4*)&wc[co4 * 4];
            s += yv.x * wv.x + yv.y * wv.y + yv.z * wv.z + yv.w * wv.w;
        }
        out[(size_t)base * 22 + it] = s;
    }
}

extern "C" void kernel_launch(void* const* d_in, const int* in_sizes, int n_in,
                              void* d_out, int out_size, void* d_ws, size_t ws_size,
                              hipStream_t stream) {
    const float* x  = (const float*)d_in[0];
    const int*   ei = (const int*)d_in[1];   // int32 (JAX x64 disabled)
    const float* W1 = (const float*)d_in[2];
    const float* b1 = (const float*)d_in[3];
    const float* W2 = (const float*)d_in[4];
    const float* b2 = (const float*)d_in[5];
    const float* cw = (const float*)d_in[6];
    const float* cb = (const float*)d_in[7];
    const float* fw = (const float*)d_in[8];
    const float* fb = (const float*)d_in[9];
    float* out = (float*)d_out;

    int N = in_sizes[0] / 8;       // 100000
    int E = in_sizes[1] / 2;       // 3200000
    const int* src = ei;
    const int* dst = ei + E;
    int NB = (N + BKT_NODES - 1) >> BKT_SHIFT;  // 391

    auto alignB = [](size_t v) { return (v + 1023) & ~(size_t)1023; };
    char* wsb = (char*)d_ws;
    size_t o = 0;
    int* bcnt = (int*)(wsb + o);      o += 2048;
    int* boff = (int*)(wsb + o);      o += 2048;
    int* bcur = (int*)(wsb + o);      o += 2048;
    int* rowstart = (int*)(wsb + o);  o += alignB((size_t)(N + 1) * 4);
    float* dinv = (float*)(wsb + o);  o += alignB((size_t)N * 4);
    int* csr = (int*)(wsb + o);       o += alignB((size_t)E * 4);
    __half2* hx = (__half2*)(wsb + o);  o += alignB((size_t)N * 8 * 2);   // [N][8] fp16
    __half* hw2 = (__half*)(wsb + o);   o += alignB((size_t)N * 32 * 2);  // [N][32] fp16
    float* B = (float*)(wsb + o);     o += (size_t)N * 64 * 4;            // g1, then g2
    int* ebuf = (int*)B;              // dead before B's first write

    hipMemsetAsync(bcnt, 0, (size_t)NB * sizeof(int), stream);
    k_hist<<<(E + 4095) / 4096, 256, 0, stream>>>(dst, bcnt, E, NB);
    k_bscan<<<1, 512, 0, stream>>>(bcnt, boff, bcur, NB, E);
    k_part<<<(E + 2047) / 2048, 256, 0, stream>>>(src, dst, bcur, ebuf, E, NB);
    k_lsort<<<NB, 256, 0, stream>>>(boff, ebuf, rowstart, dinv, csr, N, NB);

    k_hx<<<(N * 4 + 255) / 256, 256, 0, stream>>>(x, dinv, hx, N * 4);
    k_agg1f<<<(int)(((size_t)N * 64 + 255) / 256), 256, 0, stream>>>(rowstart, csr, dinv, hx, W1, b1, B, N);

    k_gemm2<<<(N + 7) / 8, 256, 0, stream>>>(B, W2, dinv, hw2, N);
    k_aggr32x<<<(int)(((size_t)N * 16 + 255) / 256), 256, 0, stream>>>(rowstart, csr, dinv, hw2, b2, B, N);

    k_head<<<(N - 2 + HROWS - 1) / HROWS, 256, 0, stream>>>(B, cw, cb, fw, fb, out, N - 2);
}

// Round 14
// 246.586 us; speedup vs baseline: 1.0210x; 1.0210x over previous
//
#include <hip/hip_runtime.h>
#include <hip/hip_fp16.h>
#include <math.h>

#define BKT_SHIFT 8
#define BKT_NODES 256
#define HROWS 64
#define PCHUNK 2048

// ---- pass 1: per-block per-bucket histogram -> cntmat[blk][NB] + bcnt ----
__global__ __launch_bounds__(256) void k_hist2(const int* __restrict__ dst,
                                               int* __restrict__ bcnt,
                                               int* __restrict__ cntmat, int E, int NB) {
    __shared__ int lh[512];
    for (int i = threadIdx.x; i < NB; i += 256) lh[i] = 0;
    __syncthreads();
    int base = blockIdx.x * PCHUNK;
    if (base + PCHUNK <= E) {
        const int4* d4 = (const int4*)(dst + base);
#pragma unroll
        for (int k = 0; k < 2; ++k) {
            int4 v = d4[k * 256 + threadIdx.x];
            atomicAdd(&lh[v.x >> BKT_SHIFT], 1);
            atomicAdd(&lh[v.y >> BKT_SHIFT], 1);
            atomicAdd(&lh[v.z >> BKT_SHIFT], 1);
            atomicAdd(&lh[v.w >> BKT_SHIFT], 1);
        }
    } else {
        for (int k = 0; k < 8; ++k) {
            int i = base + k * 256 + threadIdx.x;
            if (i < E) atomicAdd(&lh[dst[i] >> BKT_SHIFT], 1);
        }
    }
    __syncthreads();
    int* row = cntmat + (size_t)blockIdx.x * NB;
    for (int t = threadIdx.x; t < NB; t += 256) {
        int c = lh[t];
        row[t] = c;
        if (c) atomicAdd(&bcnt[t], c);
    }
}

// ---- exclusive scan over NB buckets (single block) ----
__global__ __launch_bounds__(512) void k_bscan(const int* __restrict__ bc,
                                               int* __restrict__ boff, int NB, int E) {
    __shared__ int s[512];
    __shared__ int carry;
    if (threadIdx.x == 0) carry = 0;
    __syncthreads();
    for (int base = 0; base < NB; base += 512) {
        int i = base + threadIdx.x;
        int v = (i < NB) ? bc[i] : 0;
        s[threadIdx.x] = v;
        __syncthreads();
        for (int off = 1; off < 512; off <<= 1) {
            int t = (threadIdx.x >= off) ? s[threadIdx.x - off] : 0;
            __syncthreads();
            s[threadIdx.x] += t;
            __syncthreads();
        }
        if (i < NB) boff[i] = carry + s[threadIdx.x] - v;
        __syncthreads();
        if (threadIdx.x == 0) carry += s[511];
        __syncthreads();
    }
    if (threadIdx.x == 0) boff[NB] = E;
}

// ---- per-bucket exclusive scan across blocks (in place on cntmat) ----
__global__ __launch_bounds__(256) void k_colscan(int* __restrict__ cm, int NBLK, int NB) {
    __shared__ int s[256];
    __shared__ int carry;
    int b = blockIdx.x;
    if (threadIdx.x == 0) carry = 0;
    __syncthreads();
    for (int base = 0; base < NBLK; base += 256) {
        int i = base + threadIdx.x;
        int v = (i < NBLK) ? cm[(size_t)i * NB + b] : 0;
        s[threadIdx.x] = v;
        __syncthreads();
        for (int off = 1; off < 256; off <<= 1) {
            int t = (threadIdx.x >= off) ? s[threadIdx.x - off] : 0;
            __syncthreads();
            s[threadIdx.x] += t;
            __syncthreads();
        }
        if (i < NBLK) cm[(size_t)i * NB + b] = carry + s[threadIdx.x] - v;  // exclusive
        __syncthreads();
        if (threadIdx.x == 0) carry += s[255];
        __syncthreads();
    }
}

// ---- pass 2: scatter with deterministic offsets (no global atomics) ----
__global__ __launch_bounds__(256) void k_part2(const int* __restrict__ src,
                                               const int* __restrict__ dst,
                                               const int* __restrict__ boff,
                                               const int* __restrict__ cntmat,
                                               int* __restrict__ ebuf, int E, int NB) {
    __shared__ int lh[512];
    const int* row = cntmat + (size_t)blockIdx.x * NB;
    for (int t = threadIdx.x; t < NB; t += 256) lh[t] = boff[t] + row[t];
    __syncthreads();
    int base = blockIdx.x * PCHUNK;
    if (base + PCHUNK <= E) {
        const int4* d4 = (const int4*)(dst + base);
        const int4* s4 = (const int4*)(src + base);
#pragma unroll
        for (int k = 0; k < 2; ++k) {
            int4 dv = d4[k * 256 + threadIdx.x];
            int4 sv = s4[k * 256 + threadIdx.x];
            int p;
            p = atomicAdd(&lh[dv.x >> BKT_SHIFT], 1); ebuf[p] = ((dv.x & 255) << 24) | sv.x;
            p = atomicAdd(&lh[dv.y >> BKT_SHIFT], 1); ebuf[p] = ((dv.y & 255) << 24) | sv.y;
            p = atomicAdd(&lh[dv.z >> BKT_SHIFT], 1); ebuf[p] = ((dv.z & 255) << 24) | sv.z;
            p = atomicAdd(&lh[dv.w >> BKT_SHIFT], 1); ebuf[p] = ((dv.w & 255) << 24) | sv.w;
        }
    } else {
        for (int k = 0; k < 8; ++k) {
            int i = base + k * 256 + threadIdx.x;
            if (i < E) {
                int d = dst[i];
                int p = atomicAdd(&lh[d >> BKT_SHIFT], 1);
                ebuf[p] = ((d & 255) << 24) | src[i];
            }
        }
    }
}

// ---- pass 3: per-bucket counting sort -> csr (masked src), rowstart, dinv ----
__global__ __launch_bounds__(256) void k_lsort(const int* __restrict__ boff,
                                               const int* __restrict__ ebuf,
                                               int* __restrict__ rowstart,
                                               float* __restrict__ dinv,
                                               int* __restrict__ csr, int n, int NB) {
    __shared__ int off[256];
    __shared__ int cnt[256];
    int b = blockIdx.x;
    int start = boff[b], end = boff[b + 1];
    cnt[threadIdx.x] = 0;
    __syncthreads();
    for (int i = start + threadIdx.x; i < end; i += 256)
        atomicAdd(&cnt[((unsigned)ebuf[i]) >> 24], 1);
    __syncthreads();
    int v = cnt[threadIdx.x];
    off[threadIdx.x] = v;
    __syncthreads();
    for (int o = 1; o < 256; o <<= 1) {
        int t = (threadIdx.x >= o) ? off[threadIdx.x - o] : 0;
        __syncthreads();
        off[threadIdx.x] += t;
        __syncthreads();
    }
    int excl = off[threadIdx.x] - v;
    int node = (b << BKT_SHIFT) + threadIdx.x;
    if (node < n) {
        rowstart[node] = start + excl;
        dinv[node] = rsqrtf((float)v + 1.0f);  // +1 = self-loop
    }
    __syncthreads();
    off[threadIdx.x] = excl;  // reuse as cursor
    __syncthreads();
    for (int i = start + threadIdx.x; i < end; i += 256) {
        int rec = ebuf[i];
        int d = ((unsigned)rec) >> 24;
        int pos = atomicAdd(&off[d], 1);
        csr[start + pos] = rec & 0xFFFFFF;
    }
    if (b == NB - 1 && threadIdx.x == 0) rowstart[n] = end;
}

// ---- hx = fp16(x * dinv), [N][8] ----
__global__ __launch_bounds__(256) void k_hx(const float* __restrict__ x,
                                            const float* __restrict__ dinv,
                                            __half2* __restrict__ hx, int n4) {
    int t = blockIdx.x * 256 + threadIdx.x;
    if (t >= n4) return;
    float2 v = ((const float2*)x)[t];
    float dv = dinv[t >> 2];
    hx[t] = __floats2half2_rn(v.x * dv, v.y * dv);
}

// ---- fused layer-1: aggregate hx (8 feats) then @W1+bias+ELU ----
__global__ __launch_bounds__(256) void k_agg1f(const int* __restrict__ rs, const int* __restrict__ csr,
                                               const float* __restrict__ dinv, const __half2* __restrict__ hx,
                                               const float* __restrict__ W1, const float* __restrict__ bias,
                                               float* __restrict__ g, int n) {
    __shared__ float w[512];
    for (int i = threadIdx.x; i < 512; i += 256) w[i] = W1[i];
    __syncthreads();
    int wid = (blockIdx.x * 256 + threadIdx.x) >> 6;
    if (wid >= n) return;
    int lane = threadIdx.x & 63;
    int sub = lane >> 2;        // 0..15 edge subset
    int jp = lane & 3;          // half2 index
    int start = rs[wid], end = rs[wid + 1];
    float ax = 0.f, ay = 0.f;
    int i = start + sub;
    for (; i + 16 < end; i += 32) {
        int s0 = csr[i], s1 = csr[i + 16];
        float2 f0 = __half22float2(hx[((size_t)s0 << 2) + jp]);
        float2 f1 = __half22float2(hx[((size_t)s1 << 2) + jp]);
        ax += f0.x + f1.x;
        ay += f0.y + f1.y;
    }
    for (; i < end; i += 16) {
        float2 f = __half22float2(hx[((size_t)csr[i] << 2) + jp]);
        ax += f.x; ay += f.y;
    }
    if (sub == 0) {  // self-loop row
        float2 f = __half22float2(hx[((size_t)wid << 2) + jp]);
        ax += f.x; ay += f.y;
    }
#pragma unroll
    for (int m = 4; m < 64; m <<= 1) {
        ax += __shfl_xor(ax, m);
        ay += __shfl_xor(ay, m);
    }
    float dv = dinv[wid];
    float s = 0.f;
#pragma unroll
    for (int kp = 0; kp < 4; ++kp) {
        float a = __shfl(ax, kp);
        float b = __shfl(ay, kp);
        s += a * w[(2 * kp) * 64 + lane] + b * w[(2 * kp + 1) * 64 + lane];
    }
    float v = dv * s + bias[lane];
    g[(size_t)wid * 64 + lane] = v > 0.f ? v : expm1f(v);
}

// ---- layer-2 aggregation: 4 nodes/wave, 16 lanes/node, unroll 8, no shuffles ----
__global__ __launch_bounds__(256) void k_aggr32x(const int* __restrict__ rs, const int* __restrict__ csr,
                                                 const float* __restrict__ dinv, const __half* __restrict__ hw,
                                                 const float* __restrict__ bias, float* __restrict__ g, int n) {
    int wid = (blockIdx.x * 256 + threadIdx.x) >> 4;
    if (wid >= n) return;
    int j = threadIdx.x & 15;           // feature pair (feats 2j, 2j+1)
    int start = rs[wid], end = rs[wid + 1];
    const __half2* hp = (const __half2*)hw;
    float ax = 0.f, ay = 0.f;
    int i = start;
    for (; i + 8 <= end; i += 8) {
        int s0 = csr[i],     s1 = csr[i + 1], s2 = csr[i + 2], s3 = csr[i + 3];
        int s4 = csr[i + 4], s5 = csr[i + 5], s6 = csr[i + 6], s7 = csr[i + 7];
        float2 f0 = __half22float2(hp[((size_t)s0 << 4) + j]);
        float2 f1 = __half22float2(hp[((size_t)s1 << 4) + j]);
        float2 f2 = __half22float2(hp[((size_t)s2 << 4) + j]);
        float2 f3 = __half22float2(hp[((size_t)s3 << 4) + j]);
        float2 f4 = __half22float2(hp[((size_t)s4 << 4) + j]);
        float2 f5 = __half22float2(hp[((size_t)s5 << 4) + j]);
        float2 f6 = __half22float2(hp[((size_t)s6 << 4) + j]);
        float2 f7 = __half22float2(hp[((size_t)s7 << 4) + j]);
        ax += f0.x + f1.x + f2.x + f3.x + f4.x + f5.x + f6.x + f7.x;
        ay += f0.y + f1.y + f2.y + f3.y + f4.y + f5.y + f6.y + f7.y;
    }
    for (; i < end; ++i) {
        int s = csr[i];
        float2 f = __half22float2(hp[((size_t)s << 4) + j]);
        ax += f.x; ay += f.y;
    }
    float dv = dinv[wid];
    float2 fs = __half22float2(hp[((size_t)wid << 4) + j]);
    float2 bb = ((const float2*)bias)[j];
    float vx = dv * (ax + fs.x) + bb.x;
    float vy = dv * (ay + fs.y) + bb.y;
    float2 r;
    r.x = vx > 0.f ? vx : expm1f(vx);
    r.y = vy > 0.f ? vy : expm1f(vy);
    ((float2*)(g + ((size_t)wid << 5)))[j] = r;
}

// ---- hw2 = fp16((g1 @ W2) * dinv)  (64 -> 32), single plane, plain loads ----
__global__ __launch_bounds__(256) void k_gemm2(const float* __restrict__ g1, const float* __restrict__ W2,
                                               const float* __restrict__ dinv, __half* __restrict__ hw2, int n) {
    __shared__ float w[2048];
    __shared__ float xs[512];
    for (int i = threadIdx.x; i < 2048; i += 256) w[i] = W2[i];
    int nb = blockIdx.x * 8;
    for (int i = threadIdx.x; i < 512; i += 256) {
        int r = i >> 6, c = i & 63;
        int node = nb + r;
        xs[i] = (node < n) ? g1[(size_t)node * 64 + c] : 0.f;
    }
    __syncthreads();
    int node = nb + (threadIdx.x >> 5);
    int j = threadIdx.x & 31;
    if (node >= n) return;
    const float* xr = &xs[(threadIdx.x >> 5) << 6];
    float s = 0.f;
#pragma unroll
    for (int k = 0; k < 64; ++k) s += xr[k] * w[k * 32 + j];
    hw2[(size_t)node * 32 + j] = __float2half_rn(s * dinv[node]);
}

// ---- cooperative head: conv1d(32->16,k=3)+relu+fc(16->22), 64 rows/block, float4 ----
__global__ __launch_bounds__(256) void k_head(const float* __restrict__ g2, const float* __restrict__ cw,
                                              const float* __restrict__ cb, const float* __restrict__ fw,
                                              const float* __restrict__ fb, float* __restrict__ out,
                                              int nrows) {
    __shared__ float tile[(HROWS + 2) * 36];
    __shared__ float scwT[96 * 16];
    __shared__ float ytile[HROWS * 20];
    __shared__ float sfwT[22 * 16];
    __shared__ float scb[16], sfb[22];
    int base = blockIdx.x * HROWS;
    int rcnt = nrows - base; if (rcnt > HROWS) rcnt = HROWS;
    for (int i = threadIdx.x; i < 1536; i += 256) {
        int co = i / 96, rem = i - co * 96;
        scwT[rem * 16 + co] = cw[i];
    }
    for (int i = threadIdx.x; i < 352; i += 256) {
        int co = i / 22, col = i - co * 22;
        sfwT[col * 16 + co] = fw[i];
    }
    if (threadIdx.x < 16) scb[threadIdx.x] = cb[threadIdx.x];
    if (threadIdx.x < 22) sfb[threadIdx.x] = fb[threadIdx.x];
    int nload4 = (rcnt + 2) * 8;
    for (int i = threadIdx.x; i < nload4; i += 256) {
        int r = i >> 3, c4 = i & 7;
        float4 v = *(const float4*)(g2 + (size_t)(base + r) * 32 + c4 * 4);
        *(float4*)&tile[r * 36 + c4 * 4] = v;
    }
    __syncthreads();
    int r = threadIdx.x >> 2;
    int c0 = threadIdx.x & 3;
    if (r < rcnt) {
        float4 acc = { scb[c0 * 4], scb[c0 * 4 + 1], scb[c0 * 4 + 2], scb[c0 * 4 + 3] };
#pragma unroll
        for (int k = 0; k < 3; ++k) {
            const float* tr = &tile[(r + k) * 36];
#pragma unroll
            for (int ci4 = 0; ci4 < 8; ++ci4) {
                float4 xv = *(const float4*)&tr[ci4 * 4];
#pragma unroll
                for (int q = 0; q < 4; ++q) {
                    int ci = ci4 * 4 + q;
                    float4 wv = *(const float4*)&scwT[(ci * 3 + k) * 16 + c0 * 4];
                    float xq = q == 0 ? xv.x : q == 1 ? xv.y : q == 2 ? xv.z : xv.w;
                    acc.x += xq * wv.x;
                    acc.y += xq * wv.y;
                    acc.z += xq * wv.z;
                    acc.w += xq * wv.w;
                }
            }
        }
        float4 yv;
        yv.x = acc.x > 0.f ? acc.x : 0.f;
        yv.y = acc.y > 0.f ? acc.y : 0.f;
        yv.z = acc.z > 0.f ? acc.z : 0.f;
        yv.w = acc.w > 0.f ? acc.w : 0.f;
        *(float4*)&ytile[r * 20 + c0 * 4] = yv;
    }
    __syncthreads();
    int items = rcnt * 22;
    for (int it = threadIdx.x; it < items; it += 256) {
        int row = it / 22, col = it - row * 22;
        const float* yr = &ytile[row * 20];
        const float* wc = &sfwT[col * 16];
        float s = sfb[col];
#pragma unroll
        for (int co4 = 0; co4 < 4; ++co4) {
            float4 yv = *(const float4*)&yr[co4 * 4];
            float4 wv = *(const float4*)&wc[co4 * 4];
            s += yv.x * wv.x + yv.y * wv.y + yv.z * wv.z + yv.w * wv.w;
        }
        out[(size_t)base * 22 + it] = s;
    }
}

extern "C" void kernel_launch(void* const* d_in, const int* in_sizes, int n_in,
                              void* d_out, int out_size, void* d_ws, size_t ws_size,
                              hipStream_t stream) {
    const float* x  = (const float*)d_in[0];
    const int*   ei = (const int*)d_in[1];   // int32 (JAX x64 disabled)
    const float* W1 = (const float*)d_in[2];
    const float* b1 = (const float*)d_in[3];
    const float* W2 = (const float*)d_in[4];
    const float* b2 = (const float*)d_in[5];
    const float* cw = (const float*)d_in[6];
    const float* cb = (const float*)d_in[7];
    const float* fw = (const float*)d_in[8];
    const float* fb = (const float*)d_in[9];
    float* out = (float*)d_out;

    int N = in_sizes[0] / 8;       // 100000
    int E = in_sizes[1] / 2;       // 3200000
    const int* src = ei;
    const int* dst = ei + E;
    int NB = (N + BKT_NODES - 1) >> BKT_SHIFT;   // 391
    int NBLK = (E + PCHUNK - 1) / PCHUNK;        // 1563

    auto alignB = [](size_t v) { return (v + 1023) & ~(size_t)1023; };
    char* wsb = (char*)d_ws;
    size_t o = 0;
    int* bcnt = (int*)(wsb + o);      o += 2048;
    int* boff = (int*)(wsb + o);      o += 2048;
    int* cntmat = (int*)(wsb + o);    o += alignB((size_t)NBLK * NB * 4);  // 2.44MB
    int* rowstart = (int*)(wsb + o);  o += alignB((size_t)(N + 1) * 4);
    float* dinv = (float*)(wsb + o);  o += alignB((size_t)N * 4);
    int* csr = (int*)(wsb + o);       o += alignB((size_t)E * 4);
    __half2* hx = (__half2*)(wsb + o);  o += alignB((size_t)N * 8 * 2);   // [N][8] fp16
    __half* hw2 = (__half*)(wsb + o);   o += alignB((size_t)N * 32 * 2);  // [N][32] fp16
    float* B = (float*)(wsb + o);     o += (size_t)N * 64 * 4;            // g1, then g2
    int* ebuf = (int*)B;              // dead before B's first write

    hipMemsetAsync(bcnt, 0, (size_t)NB * sizeof(int), stream);
    k_hist2<<<NBLK, 256, 0, stream>>>(dst, bcnt, cntmat, E, NB);
    k_bscan<<<1, 512, 0, stream>>>(bcnt, boff, NB, E);
    k_colscan<<<NB, 256, 0, stream>>>(cntmat, NBLK, NB);
    k_part2<<<NBLK, 256, 0, stream>>>(src, dst, boff, cntmat, ebuf, E, NB);
    k_lsort<<<NB, 256, 0, stream>>>(boff, ebuf, rowstart, dinv, csr, N, NB);

    k_hx<<<(N * 4 + 255) / 256, 256, 0, stream>>>(x, dinv, hx, N * 4);
    k_agg1f<<<(int)(((size_t)N * 64 + 255) / 256), 256, 0, stream>>>(rowstart, csr, dinv, hx, W1, b1, B, N);

    k_gemm2<<<(N + 7) / 8, 256, 0, stream>>>(B, W2, dinv, hw2, N);
    k_aggr32x<<<(int)(((size_t)N * 16 + 255) / 256), 256, 0, stream>>>(rowstart, csr, dinv, hw2, b2, B, N);

    k_head<<<(N - 2 + HROWS - 1) / HROWS, 256, 0, stream>>>(B, cw, cb, fw, fb, out, N - 2);
}

// Round 15
// 217.363 us; speedup vs baseline: 1.1582x; 1.1344x over previous
//
#include <hip/hip_runtime.h>
#include <hip/hip_fp16.h>
#include <math.h>

#define BKT_SHIFT 8
#define BKT_NODES 256
#define HROWS 64

// ---- pass 1: per-bucket histogram (int4-vectorized dst read) ----
__global__ __launch_bounds__(256) void k_hist(const int* __restrict__ dst,
                                              int* __restrict__ bcnt, int E, int NB) {
    __shared__ int lh[512];
    for (int i = threadIdx.x; i < NB; i += 256) lh[i] = 0;
    __syncthreads();
    int base = blockIdx.x * 4096;
    if (base + 4096 <= E) {
        const int4* d4 = (const int4*)(dst + base);
#pragma unroll
        for (int k = 0; k < 4; ++k) {
            int4 v = d4[k * 256 + threadIdx.x];
            atomicAdd(&lh[v.x >> BKT_SHIFT], 1);
            atomicAdd(&lh[v.y >> BKT_SHIFT], 1);
            atomicAdd(&lh[v.z >> BKT_SHIFT], 1);
            atomicAdd(&lh[v.w >> BKT_SHIFT], 1);
        }
    } else {
        for (int k = 0; k < 16; ++k) {
            int i = base + k * 256 + threadIdx.x;
            if (i < E) atomicAdd(&lh[dst[i] >> BKT_SHIFT], 1);
        }
    }
    __syncthreads();
    for (int i = threadIdx.x; i < NB; i += 256)
        if (lh[i]) atomicAdd(&bcnt[i], lh[i]);
}

// ---- exclusive scan over NB buckets (single block) ----
__global__ __launch_bounds__(512) void k_bscan(const int* __restrict__ bc,
                                               int* __restrict__ boff,
                                               int* __restrict__ bcur, int NB, int E) {
    __shared__ int s[512];
    __shared__ int carry;
    if (threadIdx.x == 0) carry = 0;
    __syncthreads();
    for (int base = 0; base < NB; base += 512) {
        int i = base + threadIdx.x;
        int v = (i < NB) ? bc[i] : 0;
        s[threadIdx.x] = v;
        __syncthreads();
        for (int off = 1; off < 512; off <<= 1) {
            int t = (threadIdx.x >= off) ? s[threadIdx.x - off] : 0;
            __syncthreads();
            s[threadIdx.x] += t;
            __syncthreads();
        }
        if (i < NB) {
            int ex = carry + s[threadIdx.x] - v;
            boff[i] = ex;
            bcur[i] = ex;
        }
        __syncthreads();
        if (threadIdx.x == 0) carry += s[511];
        __syncthreads();
    }
    if (threadIdx.x == 0) boff[NB] = E;
}

// ---- pass 2: partition edges; record = (d&255)<<24 | src ----
// 1024 threads/block, 8192 edges/block: r12's atomic count, 16 waves/block MLP
__global__ __launch_bounds__(1024) void k_part(const int* __restrict__ src,
                                               const int* __restrict__ dst,
                                               int* __restrict__ bcur,
                                               int* __restrict__ ebuf, int E, int NB) {
    __shared__ int lh[512];
    for (int i = threadIdx.x; i < NB; i += 1024) lh[i] = 0;
    __syncthreads();
    int base = blockIdx.x * 8192;
    if (base + 8192 <= E) {
        const int4* d4 = (const int4*)(dst + base);
#pragma unroll
        for (int k = 0; k < 2; ++k) {
            int4 v = d4[k * 1024 + threadIdx.x];
            atomicAdd(&lh[v.x >> BKT_SHIFT], 1);
            atomicAdd(&lh[v.y >> BKT_SHIFT], 1);
            atomicAdd(&lh[v.z >> BKT_SHIFT], 1);
            atomicAdd(&lh[v.w >> BKT_SHIFT], 1);
        }
    } else {
        for (int k = 0; k < 8; ++k) {
            int i = base + k * 1024 + threadIdx.x;
            if (i < E) atomicAdd(&lh[dst[i] >> BKT_SHIFT], 1);
        }
    }
    __syncthreads();
    for (int t = threadIdx.x; t < NB; t += 1024) {
        int c = lh[t];
        lh[t] = c ? atomicAdd(&bcur[t], c) : 0;
    }
    __syncthreads();
    if (base + 8192 <= E) {
        const int4* d4 = (const int4*)(dst + base);
        const int4* s4 = (const int4*)(src + base);
#pragma unroll
        for (int k = 0; k < 2; ++k) {
            int4 dv = d4[k * 1024 + threadIdx.x];
            int4 sv = s4[k * 1024 + threadIdx.x];
            int p;
            p = atomicAdd(&lh[dv.x >> BKT_SHIFT], 1); ebuf[p] = ((dv.x & 255) << 24) | sv.x;
            p = atomicAdd(&lh[dv.y >> BKT_SHIFT], 1); ebuf[p] = ((dv.y & 255) << 24) | sv.y;
            p = atomicAdd(&lh[dv.z >> BKT_SHIFT], 1); ebuf[p] = ((dv.z & 255) << 24) | sv.z;
            p = atomicAdd(&lh[dv.w >> BKT_SHIFT], 1); ebuf[p] = ((dv.w & 255) << 24) | sv.w;
        }
    } else {
        for (int k = 0; k < 8; ++k) {
            int i = base + k * 1024 + threadIdx.x;
            if (i < E) {
                int d = dst[i];
                int p = atomicAdd(&lh[d >> BKT_SHIFT], 1);
                ebuf[p] = ((d & 255) << 24) | src[i];
            }
        }
    }
}

// ---- pass 3: per-bucket counting sort -> csr (masked src), rowstart, dinv ----
__global__ __launch_bounds__(256) void k_lsort(const int* __restrict__ boff,
                                               const int* __restrict__ ebuf,
                                               int* __restrict__ rowstart,
                                               float* __restrict__ dinv,
                                               int* __restrict__ csr, int n, int NB) {
    __shared__ int off[256];
    __shared__ int cnt[256];
    int b = blockIdx.x;
    int start = boff[b], end = boff[b + 1];
    cnt[threadIdx.x] = 0;
    __syncthreads();
    for (int i = start + threadIdx.x; i < end; i += 256)
        atomicAdd(&cnt[((unsigned)ebuf[i]) >> 24], 1);
    __syncthreads();
    int v = cnt[threadIdx.x];
    off[threadIdx.x] = v;
    __syncthreads();
    for (int o = 1; o < 256; o <<= 1) {
        int t = (threadIdx.x >= o) ? off[threadIdx.x - o] : 0;
        __syncthreads();
        off[threadIdx.x] += t;
        __syncthreads();
    }
    int excl = off[threadIdx.x] - v;
    int node = (b << BKT_SHIFT) + threadIdx.x;
    if (node < n) {
        rowstart[node] = start + excl;
        dinv[node] = rsqrtf((float)v + 1.0f);  // +1 = self-loop
    }
    __syncthreads();
    off[threadIdx.x] = excl;  // reuse as cursor
    __syncthreads();
    for (int i = start + threadIdx.x; i < end; i += 256) {
        int rec = ebuf[i];
        int d = ((unsigned)rec) >> 24;
        int pos = atomicAdd(&off[d], 1);
        csr[start + pos] = rec & 0xFFFFFF;
    }
    if (b == NB - 1 && threadIdx.x == 0) rowstart[n] = end;
}

// ---- hx = fp16(x * dinv), [N][8] ----
__global__ __launch_bounds__(256) void k_hx(const float* __restrict__ x,
                                            const float* __restrict__ dinv,
                                            __half2* __restrict__ hx, int n4) {
    int t = blockIdx.x * 256 + threadIdx.x;
    if (t >= n4) return;
    float2 v = ((const float2*)x)[t];
    float dv = dinv[t >> 2];
    hx[t] = __floats2half2_rn(v.x * dv, v.y * dv);
}

// ---- fused layer-1: aggregate hx (8 feats) then @W1+bias+ELU ----
__global__ __launch_bounds__(256) void k_agg1f(const int* __restrict__ rs, const int* __restrict__ csr,
                                               const float* __restrict__ dinv, const __half2* __restrict__ hx,
                                               const float* __restrict__ W1, const float* __restrict__ bias,
                                               float* __restrict__ g, int n) {
    __shared__ float w[512];
    for (int i = threadIdx.x; i < 512; i += 256) w[i] = W1[i];
    __syncthreads();
    int wid = (blockIdx.x * 256 + threadIdx.x) >> 6;
    if (wid >= n) return;
    int lane = threadIdx.x & 63;
    int sub = lane >> 2;        // 0..15 edge subset
    int jp = lane & 3;          // half2 index
    int start = rs[wid], end = rs[wid + 1];
    float ax = 0.f, ay = 0.f;
    int i = start + sub;
    for (; i + 16 < end; i += 32) {
        int s0 = csr[i], s1 = csr[i + 16];
        float2 f0 = __half22float2(hx[((size_t)s0 << 2) + jp]);
        float2 f1 = __half22float2(hx[((size_t)s1 << 2) + jp]);
        ax += f0.x + f1.x;
        ay += f0.y + f1.y;
    }
    for (; i < end; i += 16) {
        float2 f = __half22float2(hx[((size_t)csr[i] << 2) + jp]);
        ax += f.x; ay += f.y;
    }
    if (sub == 0) {  // self-loop row
        float2 f = __half22float2(hx[((size_t)wid << 2) + jp]);
        ax += f.x; ay += f.y;
    }
#pragma unroll
    for (int m = 4; m < 64; m <<= 1) {
        ax += __shfl_xor(ax, m);
        ay += __shfl_xor(ay, m);
    }
    float dv = dinv[wid];
    float s = 0.f;
#pragma unroll
    for (int kp = 0; kp < 4; ++kp) {
        float a = __shfl(ax, kp);
        float b = __shfl(ay, kp);
        s += a * w[(2 * kp) * 64 + lane] + b * w[(2 * kp + 1) * 64 + lane];
    }
    float v = dv * s + bias[lane];
    g[(size_t)wid * 64 + lane] = v > 0.f ? v : expm1f(v);
}

// ---- layer-2 aggregation: 4 nodes/wave, 16 lanes/node, unroll 8, no shuffles ----
__global__ __launch_bounds__(256) void k_aggr32x(const int* __restrict__ rs, const int* __restrict__ csr,
                                                 const float* __restrict__ dinv, const __half* __restrict__ hw,
                                                 const float* __restrict__ bias, float* __restrict__ g, int n) {
    int wid = (blockIdx.x * 256 + threadIdx.x) >> 4;
    if (wid >= n) return;
    int j = threadIdx.x & 15;           // feature pair (feats 2j, 2j+1)
    int start = rs[wid], end = rs[wid + 1];
    const __half2* hp = (const __half2*)hw;
    float ax = 0.f, ay = 0.f;
    int i = start;
    for (; i + 8 <= end; i += 8) {
        int s0 = csr[i],     s1 = csr[i + 1], s2 = csr[i + 2], s3 = csr[i + 3];
        int s4 = csr[i + 4], s5 = csr[i + 5], s6 = csr[i + 6], s7 = csr[i + 7];
        float2 f0 = __half22float2(hp[((size_t)s0 << 4) + j]);
        float2 f1 = __half22float2(hp[((size_t)s1 << 4) + j]);
        float2 f2 = __half22float2(hp[((size_t)s2 << 4) + j]);
        float2 f3 = __half22float2(hp[((size_t)s3 << 4) + j]);
        float2 f4 = __half22float2(hp[((size_t)s4 << 4) + j]);
        float2 f5 = __half22float2(hp[((size_t)s5 << 4) + j]);
        float2 f6 = __half22float2(hp[((size_t)s6 << 4) + j]);
        float2 f7 = __half22float2(hp[((size_t)s7 << 4) + j]);
        ax += f0.x + f1.x + f2.x + f3.x + f4.x + f5.x + f6.x + f7.x;
        ay += f0.y + f1.y + f2.y + f3.y + f4.y + f5.y + f6.y + f7.y;
    }
    for (; i < end; ++i) {
        int s = csr[i];
        float2 f = __half22float2(hp[((size_t)s << 4) + j]);
        ax += f.x; ay += f.y;
    }
    float dv = dinv[wid];
    float2 fs = __half22float2(hp[((size_t)wid << 4) + j]);
    float2 bb = ((const float2*)bias)[j];
    float vx = dv * (ax + fs.x) + bb.x;
    float vy = dv * (ay + fs.y) + bb.y;
    float2 r;
    r.x = vx > 0.f ? vx : expm1f(vx);
    r.y = vy > 0.f ? vy : expm1f(vy);
    ((float2*)(g + ((size_t)wid << 5)))[j] = r;
}

// ---- hw2 = fp16((g1 @ W2) * dinv)  (64 -> 32), single plane, plain loads ----
__global__ __launch_bounds__(256) void k_gemm2(const float* __restrict__ g1, const float* __restrict__ W2,
                                               const float* __restrict__ dinv, __half* __restrict__ hw2, int n) {
    __shared__ float w[2048];
    __shared__ float xs[512];
    for (int i = threadIdx.x; i < 2048; i += 256) w[i] = W2[i];
    int nb = blockIdx.x * 8;
    for (int i = threadIdx.x; i < 512; i += 256) {
        int r = i >> 6, c = i & 63;
        int node = nb + r;
        xs[i] = (node < n) ? g1[(size_t)node * 64 + c] : 0.f;
    }
    __syncthreads();
    int node = nb + (threadIdx.x >> 5);
    int j = threadIdx.x & 31;
    if (node >= n) return;
    const float* xr = &xs[(threadIdx.x >> 5) << 6];
    float s = 0.f;
#pragma unroll
    for (int k = 0; k < 64; ++k) s += xr[k] * w[k * 32 + j];
    hw2[(size_t)node * 32 + j] = __float2half_rn(s * dinv[node]);
}

// ---- cooperative head: conv1d(32->16,k=3)+relu+fc(16->22), 64 rows/block, float4 ----
__global__ __launch_bounds__(256) void k_head(const float* __restrict__ g2, const float* __restrict__ cw,
                                              const float* __restrict__ cb, const float* __restrict__ fw,
                                              const float* __restrict__ fb, float* __restrict__ out,
                                              int nrows) {
    __shared__ float tile[(HROWS + 2) * 36];
    __shared__ float scwT[96 * 16];
    __shared__ float ytile[HROWS * 20];
    __shared__ float sfwT[22 * 16];
    __shared__ float scb[16], sfb[22];
    int base = blockIdx.x * HROWS;
    int rcnt = nrows - base; if (rcnt > HROWS) rcnt = HROWS;
    for (int i = threadIdx.x; i < 1536; i += 256) {
        int co = i / 96, rem = i - co * 96;
        scwT[rem * 16 + co] = cw[i];
    }
    for (int i = threadIdx.x; i < 352; i += 256) {
        int co = i / 22, col = i - co * 22;
        sfwT[col * 16 + co] = fw[i];
    }
    if (threadIdx.x < 16) scb[threadIdx.x] = cb[threadIdx.x];
    if (threadIdx.x < 22) sfb[threadIdx.x] = fb[threadIdx.x];
    int nload4 = (rcnt + 2) * 8;
    for (int i = threadIdx.x; i < nload4; i += 256) {
        int r = i >> 3, c4 = i & 7;
        float4 v = *(const float4*)(g2 + (size_t)(base + r) * 32 + c4 * 4);
        *(float4*)&tile[r * 36 + c4 * 4] = v;
    }
    __syncthreads();
    int r = threadIdx.x >> 2;
    int c0 = threadIdx.x & 3;
    if (r < rcnt) {
        float4 acc = { scb[c0 * 4], scb[c0 * 4 + 1], scb[c0 * 4 + 2], scb[c0 * 4 + 3] };
#pragma unroll
        for (int k = 0; k < 3; ++k) {
            const float* tr = &tile[(r + k) * 36];
#pragma unroll
            for (int ci4 = 0; ci4 < 8; ++ci4) {
                float4 xv = *(const float4*)&tr[ci4 * 4];
#pragma unroll
                for (int q = 0; q < 4; ++q) {
                    int ci = ci4 * 4 + q;
                    float4 wv = *(const float4*)&scwT[(ci * 3 + k) * 16 + c0 * 4];
                    float xq = q == 0 ? xv.x : q == 1 ? xv.y : q == 2 ? xv.z : xv.w;
                    acc.x += xq * wv.x;
                    acc.y += xq * wv.y;
                    acc.z += xq * wv.z;
                    acc.w += xq * wv.w;
                }
            }
        }
        float4 yv;
        yv.x = acc.x > 0.f ? acc.x : 0.f;
        yv.y = acc.y > 0.f ? acc.y : 0.f;
        yv.z = acc.z > 0.f ? acc.z : 0.f;
        yv.w = acc.w > 0.f ? acc.w : 0.f;
        *(float4*)&ytile[r * 20 + c0 * 4] = yv;
    }
    __syncthreads();
    int items = rcnt * 22;
    for (int it = threadIdx.x; it < items; it += 256) {
        int row = it / 22, col = it - row * 22;
        const float* yr = &ytile[row * 20];
        const float* wc = &sfwT[col * 16];
        float s = sfb[col];
#pragma unroll
        for (int co4 = 0; co4 < 4; ++co4) {
            float4 yv = *(const float4*)&yr[co4 * 4];
            float4 wv = *(const float4*)&wc[co4 * 4];
            s += yv.x * wv.x + yv.y * wv.y + yv.z * wv.z + yv.w * wv.w;
        }
        out[(size_t)base * 22 + it] = s;
    }
}

extern "C" void kernel_launch(void* const* d_in, const int* in_sizes, int n_in,
                              void* d_out, int out_size, void* d_ws, size_t ws_size,
                              hipStream_t stream) {
    const float* x  = (const float*)d_in[0];
    const int*   ei = (const int*)d_in[1];   // int32 (JAX x64 disabled)
    const float* W1 = (const float*)d_in[2];
    const float* b1 = (const float*)d_in[3];
    const float* W2 = (const float*)d_in[4];
    const float* b2 = (const float*)d_in[5];
    const float* cw = (const float*)d_in[6];
    const float* cb = (const float*)d_in[7];
    const float* fw = (const float*)d_in[8];
    const float* fb = (const float*)d_in[9];
    float* out = (float*)d_out;

    int N = in_sizes[0] / 8;       // 100000
    int E = in_sizes[1] / 2;       // 3200000
    const int* src = ei;
    const int* dst = ei + E;
    int NB = (N + BKT_NODES - 1) >> BKT_SHIFT;  // 391

    auto alignB = [](size_t v) { return (v + 1023) & ~(size_t)1023; };
    char* wsb = (char*)d_ws;
    size_t o = 0;
    int* bcnt = (int*)(wsb + o);      o += 2048;
    int* boff = (int*)(wsb + o);      o += 2048;
    int* bcur = (int*)(wsb + o);      o += 2048;
    int* rowstart = (int*)(wsb + o);  o += alignB((size_t)(N + 1) * 4);
    float* dinv = (float*)(wsb + o);  o += alignB((size_t)N * 4);
    int* csr = (int*)(wsb + o);       o += alignB((size_t)E * 4);
    __half2* hx = (__half2*)(wsb + o);  o += alignB((size_t)N * 8 * 2);   // [N][8] fp16
    __half* hw2 = (__half*)(wsb + o);   o += alignB((size_t)N * 32 * 2);  // [N][32] fp16
    float* B = (float*)(wsb + o);     o += (size_t)N * 64 * 4;            // g1, then g2
    int* ebuf = (int*)B;              // dead before B's first write

    hipMemsetAsync(bcnt, 0, (size_t)NB * sizeof(int), stream);
    k_hist<<<(E + 4095) / 4096, 256, 0, stream>>>(dst, bcnt, E, NB);
    k_bscan<<<1, 512, 0, stream>>>(bcnt, boff, bcur, NB, E);
    k_part<<<(E + 8191) / 8192, 1024, 0, stream>>>(src, dst, bcur, ebuf, E, NB);
    k_lsort<<<NB, 256, 0, stream>>>(boff, ebuf, rowstart, dinv, csr, N, NB);

    k_hx<<<(N * 4 + 255) / 256, 256, 0, stream>>>(x, dinv, hx, N * 4);
    k_agg1f<<<(int)(((size_t)N * 64 + 255) / 256), 256, 0, stream>>>(rowstart, csr, dinv, hx, W1, b1, B, N);

    k_gemm2<<<(N + 7) / 8, 256, 0, stream>>>(B, W2, dinv, hw2, N);
    k_aggr32x<<<(int)(((size_t)N * 16 + 255) / 256), 256, 0, stream>>>(rowstart, csr, dinv, hw2, b2, B, N);

    k_head<<<(N - 2 + HROWS - 1) / HROWS, 256, 0, stream>>>(B, cw, cb, fw, fb, out, N - 2);
}

// Round 16
// 207.598 us; speedup vs baseline: 1.2127x; 1.0470x over previous
//
#include <hip/hip_runtime.h>
#include <hip/hip_fp16.h>
#include <math.h>

#define BKT_SHIFT 8
#define BKT_NODES 256
#define HROWS 64

// ---- pass 1: per-bucket histogram (int4-vectorized dst read) ----
__global__ __launch_bounds__(256) void k_hist(const int* __restrict__ dst,
                                              int* __restrict__ bcnt, int E, int NB) {
    __shared__ int lh[512];
    for (int i = threadIdx.x; i < NB; i += 256) lh[i] = 0;
    __syncthreads();
    int base = blockIdx.x * 4096;
    if (base + 4096 <= E) {
        const int4* d4 = (const int4*)(dst + base);
#pragma unroll
        for (int k = 0; k < 4; ++k) {
            int4 v = d4[k * 256 + threadIdx.x];
            atomicAdd(&lh[v.x >> BKT_SHIFT], 1);
            atomicAdd(&lh[v.y >> BKT_SHIFT], 1);
            atomicAdd(&lh[v.z >> BKT_SHIFT], 1);
            atomicAdd(&lh[v.w >> BKT_SHIFT], 1);
        }
    } else {
        for (int k = 0; k < 16; ++k) {
            int i = base + k * 256 + threadIdx.x;
            if (i < E) atomicAdd(&lh[dst[i] >> BKT_SHIFT], 1);
        }
    }
    __syncthreads();
    for (int i = threadIdx.x; i < NB; i += 256)
        if (lh[i]) atomicAdd(&bcnt[i], lh[i]);
}

// ---- exclusive scan over NB buckets (single block) ----
__global__ __launch_bounds__(512) void k_bscan(const int* __restrict__ bc,
                                               int* __restrict__ boff,
                                               int* __restrict__ bcur, int NB, int E) {
    __shared__ int s[512];
    __shared__ int carry;
    if (threadIdx.x == 0) carry = 0;
    __syncthreads();
    for (int base = 0; base < NB; base += 512) {
        int i = base + threadIdx.x;
        int v = (i < NB) ? bc[i] : 0;
        s[threadIdx.x] = v;
        __syncthreads();
        for (int off = 1; off < 512; off <<= 1) {
            int t = (threadIdx.x >= off) ? s[threadIdx.x - off] : 0;
            __syncthreads();
            s[threadIdx.x] += t;
            __syncthreads();
        }
        if (i < NB) {
            int ex = carry + s[threadIdx.x] - v;
            boff[i] = ex;
            bcur[i] = ex;
        }
        __syncthreads();
        if (threadIdx.x == 0) carry += s[511];
        __syncthreads();
    }
    if (threadIdx.x == 0) boff[NB] = E;
}

// ---- pass 2: partition edges; record = (d&255)<<24 | src ----
__global__ __launch_bounds__(1024) void k_part(const int* __restrict__ src,
                                               const int* __restrict__ dst,
                                               int* __restrict__ bcur,
                                               int* __restrict__ ebuf, int E, int NB) {
    __shared__ int lh[512];
    for (int i = threadIdx.x; i < NB; i += 1024) lh[i] = 0;
    __syncthreads();
    int base = blockIdx.x * 8192;
    if (base + 8192 <= E) {
        const int4* d4 = (const int4*)(dst + base);
#pragma unroll
        for (int k = 0; k < 2; ++k) {
            int4 v = d4[k * 1024 + threadIdx.x];
            atomicAdd(&lh[v.x >> BKT_SHIFT], 1);
            atomicAdd(&lh[v.y >> BKT_SHIFT], 1);
            atomicAdd(&lh[v.z >> BKT_SHIFT], 1);
            atomicAdd(&lh[v.w >> BKT_SHIFT], 1);
        }
    } else {
        for (int k = 0; k < 8; ++k) {
            int i = base + k * 1024 + threadIdx.x;
            if (i < E) atomicAdd(&lh[dst[i] >> BKT_SHIFT], 1);
        }
    }
    __syncthreads();
    for (int t = threadIdx.x; t < NB; t += 1024) {
        int c = lh[t];
        lh[t] = c ? atomicAdd(&bcur[t], c) : 0;
    }
    __syncthreads();
    if (base + 8192 <= E) {
        const int4* d4 = (const int4*)(dst + base);
        const int4* s4 = (const int4*)(src + base);
#pragma unroll
        for (int k = 0; k < 2; ++k) {
            int4 dv = d4[k * 1024 + threadIdx.x];
            int4 sv = s4[k * 1024 + threadIdx.x];
            int p;
            p = atomicAdd(&lh[dv.x >> BKT_SHIFT], 1); ebuf[p] = ((dv.x & 255) << 24) | sv.x;
            p = atomicAdd(&lh[dv.y >> BKT_SHIFT], 1); ebuf[p] = ((dv.y & 255) << 24) | sv.y;
            p = atomicAdd(&lh[dv.z >> BKT_SHIFT], 1); ebuf[p] = ((dv.z & 255) << 24) | sv.z;
            p = atomicAdd(&lh[dv.w >> BKT_SHIFT], 1); ebuf[p] = ((dv.w & 255) << 24) | sv.w;
        }
    } else {
        for (int k = 0; k < 8; ++k) {
            int i = base + k * 1024 + threadIdx.x;
            if (i < E) {
                int d = dst[i];
                int p = atomicAdd(&lh[d >> BKT_SHIFT], 1);
                ebuf[p] = ((d & 255) << 24) | src[i];
            }
        }
    }
}

// ---- pass 3: per-bucket counting sort -> csr (masked src), rowstart, dinv ----
__global__ __launch_bounds__(256) void k_lsort(const int* __restrict__ boff,
                                               const int* __restrict__ ebuf,
                                               int* __restrict__ rowstart,
                                               float* __restrict__ dinv,
                                               int* __restrict__ csr, int n, int NB) {
    __shared__ int off[256];
    __shared__ int cnt[256];
    int b = blockIdx.x;
    int start = boff[b], end = boff[b + 1];
    cnt[threadIdx.x] = 0;
    __syncthreads();
    for (int i = start + threadIdx.x; i < end; i += 256)
        atomicAdd(&cnt[((unsigned)ebuf[i]) >> 24], 1);
    __syncthreads();
    int v = cnt[threadIdx.x];
    off[threadIdx.x] = v;
    __syncthreads();
    for (int o = 1; o < 256; o <<= 1) {
        int t = (threadIdx.x >= o) ? off[threadIdx.x - o] : 0;
        __syncthreads();
        off[threadIdx.x] += t;
        __syncthreads();
    }
    int excl = off[threadIdx.x] - v;
    int node = (b << BKT_SHIFT) + threadIdx.x;
    if (node < n) {
        rowstart[node] = start + excl;
        dinv[node] = rsqrtf((float)v + 1.0f);  // +1 = self-loop
    }
    __syncthreads();
    off[threadIdx.x] = excl;  // reuse as cursor
    __syncthreads();
    for (int i = start + threadIdx.x; i < end; i += 256) {
        int rec = ebuf[i];
        int d = ((unsigned)rec) >> 24;
        int pos = atomicAdd(&off[d], 1);
        csr[start + pos] = rec & 0xFFFFFF;
    }
    if (b == NB - 1 && threadIdx.x == 0) rowstart[n] = end;
}

// ---- hx = fp16(x * dinv), [N][8] ----
__global__ __launch_bounds__(256) void k_hx(const float* __restrict__ x,
                                            const float* __restrict__ dinv,
                                            __half2* __restrict__ hx, int n4) {
    int t = blockIdx.x * 256 + threadIdx.x;
    if (t >= n4) return;
    float2 v = ((const float2*)x)[t];
    float dv = dinv[t >> 2];
    hx[t] = __floats2half2_rn(v.x * dv, v.y * dv);
}

// ---- fused layer-1: 4 nodes/wave? no: 16 nodes/wave, 4 lanes/node, serial edges,
//      quad-allgather then each lane computes 16 of 64 outputs ----
__global__ __launch_bounds__(256) void k_agg1x(const int* __restrict__ rs, const int* __restrict__ csr,
                                               const float* __restrict__ dinv, const __half2* __restrict__ hx,
                                               const float* __restrict__ W1, const float* __restrict__ bias,
                                               float* __restrict__ g, int n) {
    __shared__ float w[512];   // W1 [8][64]
    __shared__ float sb[64];
    for (int i = threadIdx.x; i < 512; i += 256) w[i] = W1[i];
    if (threadIdx.x < 64) sb[threadIdx.x] = bias[threadIdx.x];
    __syncthreads();
    int wid = (blockIdx.x * 256 + threadIdx.x) >> 2;   // node
    if (wid >= n) return;
    int jp = threadIdx.x & 3;          // half2 index (feats 2jp, 2jp+1)
    int start = rs[wid], end = rs[wid + 1];
    float ax = 0.f, ay = 0.f;
    int i = start;
    for (; i + 8 <= end; i += 8) {
        int s0 = csr[i],     s1 = csr[i + 1], s2 = csr[i + 2], s3 = csr[i + 3];
        int s4 = csr[i + 4], s5 = csr[i + 5], s6 = csr[i + 6], s7 = csr[i + 7];
        float2 f0 = __half22float2(hx[((size_t)s0 << 2) + jp]);
        float2 f1 = __half22float2(hx[((size_t)s1 << 2) + jp]);
        float2 f2 = __half22float2(hx[((size_t)s2 << 2) + jp]);
        float2 f3 = __half22float2(hx[((size_t)s3 << 2) + jp]);
        float2 f4 = __half22float2(hx[((size_t)s4 << 2) + jp]);
        float2 f5 = __half22float2(hx[((size_t)s5 << 2) + jp]);
        float2 f6 = __half22float2(hx[((size_t)s6 << 2) + jp]);
        float2 f7 = __half22float2(hx[((size_t)s7 << 2) + jp]);
        ax += f0.x + f1.x + f2.x + f3.x + f4.x + f5.x + f6.x + f7.x;
        ay += f0.y + f1.y + f2.y + f3.y + f4.y + f5.y + f6.y + f7.y;
    }
    for (; i < end; ++i) {
        float2 f = __half22float2(hx[((size_t)csr[i] << 2) + jp]);
        ax += f.x; ay += f.y;
    }
    {   // self-loop row
        float2 f = __half22float2(hx[((size_t)wid << 2) + jp]);
        ax += f.x; ay += f.y;
    }
    // quad allgather: each lane obtains all 8 aggregated features, tagged by source lane
    float bx = __shfl_xor(ax, 1), by = __shfl_xor(ay, 1);   // from lane jp^1
    float cx = __shfl_xor(ax, 2), cy = __shfl_xor(ay, 2);   // from lane jp^2
    float dx = __shfl_xor(bx, 2), dy = __shfl_xor(by, 2);   // from lane jp^3
    float dv = dinv[wid];
    int fb = jp * 16;   // this lane's output slice [fb, fb+16)
    const float* r0 = &w[(2 * jp) * 64 + fb];          const float* r1 = r0 + 64;
    const float* r2 = &w[(2 * (jp ^ 1)) * 64 + fb];    const float* r3 = r2 + 64;
    const float* r4 = &w[(2 * (jp ^ 2)) * 64 + fb];    const float* r5 = r4 + 64;
    const float* r6 = &w[(2 * (jp ^ 3)) * 64 + fb];    const float* r7 = r6 + 64;
    float* gout = g + (size_t)wid * 64 + fb;
    const float* sbp = &sb[fb];
#pragma unroll
    for (int m4 = 0; m4 < 4; ++m4) {
        float4 wa = *(const float4*)&r0[m4 * 4];
        float4 wb = *(const float4*)&r1[m4 * 4];
        float4 wc = *(const float4*)&r2[m4 * 4];
        float4 wd = *(const float4*)&r3[m4 * 4];
        float4 we = *(const float4*)&r4[m4 * 4];
        float4 wf = *(const float4*)&r5[m4 * 4];
        float4 wg = *(const float4*)&r6[m4 * 4];
        float4 wh = *(const float4*)&r7[m4 * 4];
        float4 o;
        o.x = dv * (ax * wa.x + ay * wb.x + bx * wc.x + by * wd.x + cx * we.x + cy * wf.x + dx * wg.x + dy * wh.x) + sbp[m4 * 4 + 0];
        o.y = dv * (ax * wa.y + ay * wb.y + bx * wc.y + by * wd.y + cx * we.y + cy * wf.y + dx * wg.y + dy * wh.y) + sbp[m4 * 4 + 1];
        o.z = dv * (ax * wa.z + ay * wb.z + bx * wc.z + by * wd.z + cx * we.z + cy * wf.z + dx * wg.z + dy * wh.z) + sbp[m4 * 4 + 2];
        o.w = dv * (ax * wa.w + ay * wb.w + bx * wc.w + by * wd.w + cx * we.w + cy * wf.w + dx * wg.w + dy * wh.w) + sbp[m4 * 4 + 3];
        o.x = o.x > 0.f ? o.x : expm1f(o.x);
        o.y = o.y > 0.f ? o.y : expm1f(o.y);
        o.z = o.z > 0.f ? o.z : expm1f(o.z);
        o.w = o.w > 0.f ? o.w : expm1f(o.w);
        *(float4*)&gout[m4 * 4] = o;
    }
}

// ---- layer-2 aggregation: 4 nodes/wave, 16 lanes/node, unroll 8, no shuffles ----
__global__ __launch_bounds__(256) void k_aggr32x(const int* __restrict__ rs, const int* __restrict__ csr,
                                                 const float* __restrict__ dinv, const __half* __restrict__ hw,
                                                 const float* __restrict__ bias, float* __restrict__ g, int n) {
    int wid = (blockIdx.x * 256 + threadIdx.x) >> 4;
    if (wid >= n) return;
    int j = threadIdx.x & 15;           // feature pair (feats 2j, 2j+1)
    int start = rs[wid], end = rs[wid + 1];
    const __half2* hp = (const __half2*)hw;
    float ax = 0.f, ay = 0.f;
    int i = start;
    for (; i + 8 <= end; i += 8) {
        int s0 = csr[i],     s1 = csr[i + 1], s2 = csr[i + 2], s3 = csr[i + 3];
        int s4 = csr[i + 4], s5 = csr[i + 5], s6 = csr[i + 6], s7 = csr[i + 7];
        float2 f0 = __half22float2(hp[((size_t)s0 << 4) + j]);
        float2 f1 = __half22float2(hp[((size_t)s1 << 4) + j]);
        float2 f2 = __half22float2(hp[((size_t)s2 << 4) + j]);
        float2 f3 = __half22float2(hp[((size_t)s3 << 4) + j]);
        float2 f4 = __half22float2(hp[((size_t)s4 << 4) + j]);
        float2 f5 = __half22float2(hp[((size_t)s5 << 4) + j]);
        float2 f6 = __half22float2(hp[((size_t)s6 << 4) + j]);
        float2 f7 = __half22float2(hp[((size_t)s7 << 4) + j]);
        ax += f0.x + f1.x + f2.x + f3.x + f4.x + f5.x + f6.x + f7.x;
        ay += f0.y + f1.y + f2.y + f3.y + f4.y + f5.y + f6.y + f7.y;
    }
    for (; i < end; ++i) {
        int s = csr[i];
        float2 f = __half22float2(hp[((size_t)s << 4) + j]);
        ax += f.x; ay += f.y;
    }
    float dv = dinv[wid];
    float2 fs = __half22float2(hp[((size_t)wid << 4) + j]);
    float2 bb = ((const float2*)bias)[j];
    float vx = dv * (ax + fs.x) + bb.x;
    float vy = dv * (ay + fs.y) + bb.y;
    float2 r;
    r.x = vx > 0.f ? vx : expm1f(vx);
    r.y = vy > 0.f ? vy : expm1f(vy);
    ((float2*)(g + ((size_t)wid << 5)))[j] = r;
}

// ---- hw2 = fp16((g1 @ W2) * dinv)  (64 -> 32), single plane, plain loads ----
__global__ __launch_bounds__(256) void k_gemm2(const float* __restrict__ g1, const float* __restrict__ W2,
                                               const float* __restrict__ dinv, __half* __restrict__ hw2, int n) {
    __shared__ float w[2048];
    __shared__ float xs[512];
    for (int i = threadIdx.x; i < 2048; i += 256) w[i] = W2[i];
    int nb = blockIdx.x * 8;
    for (int i = threadIdx.x; i < 512; i += 256) {
        int r = i >> 6, c = i & 63;
        int node = nb + r;
        xs[i] = (node < n) ? g1[(size_t)node * 64 + c] : 0.f;
    }
    __syncthreads();
    int node = nb + (threadIdx.x >> 5);
    int j = threadIdx.x & 31;
    if (node >= n) return;
    const float* xr = &xs[(threadIdx.x >> 5) << 6];
    float s = 0.f;
#pragma unroll
    for (int k = 0; k < 64; ++k) s += xr[k] * w[k * 32 + j];
    hw2[(size_t)node * 32 + j] = __float2half_rn(s * dinv[node]);
}

// ---- cooperative head: conv1d(32->16,k=3)+relu+fc(16->22), 64 rows/block, float4 ----
__global__ __launch_bounds__(256) void k_head(const float* __restrict__ g2, const float* __restrict__ cw,
                                              const float* __restrict__ cb, const float* __restrict__ fw,
                                              const float* __restrict__ fb, float* __restrict__ out,
                                              int nrows) {
    __shared__ float tile[(HROWS + 2) * 36];
    __shared__ float scwT[96 * 16];
    __shared__ float ytile[HROWS * 20];
    __shared__ float sfwT[22 * 16];
    __shared__ float scb[16], sfb[22];
    int base = blockIdx.x * HROWS;
    int rcnt = nrows - base; if (rcnt > HROWS) rcnt = HROWS;
    for (int i = threadIdx.x; i < 1536; i += 256) {
        int co = i / 96, rem = i - co * 96;
        scwT[rem * 16 + co] = cw[i];
    }
    for (int i = threadIdx.x; i < 352; i += 256) {
        int co = i / 22, col = i - co * 22;
        sfwT[col * 16 + co] = fw[i];
    }
    if (threadIdx.x < 16) scb[threadIdx.x] = cb[threadIdx.x];
    if (threadIdx.x < 22) sfb[threadIdx.x] = fb[threadIdx.x];
    int nload4 = (rcnt + 2) * 8;
    for (int i = threadIdx.x; i < nload4; i += 256) {
        int r = i >> 3, c4 = i & 7;
        float4 v = *(const float4*)(g2 + (size_t)(base + r) * 32 + c4 * 4);
        *(float4*)&tile[r * 36 + c4 * 4] = v;
    }
    __syncthreads();
    int r = threadIdx.x >> 2;
    int c0 = threadIdx.x & 3;
    if (r < rcnt) {
        float4 acc = { scb[c0 * 4], scb[c0 * 4 + 1], scb[c0 * 4 + 2], scb[c0 * 4 + 3] };
#pragma unroll
        for (int k = 0; k < 3; ++k) {
            const float* tr = &tile[(r + k) * 36];
#pragma unroll
            for (int ci4 = 0; ci4 < 8; ++ci4) {
                float4 xv = *(const float4*)&tr[ci4 * 4];
#pragma unroll
                for (int q = 0; q < 4; ++q) {
                    int ci = ci4 * 4 + q;
                    float4 wv = *(const float4*)&scwT[(ci * 3 + k) * 16 + c0 * 4];
                    float xq = q == 0 ? xv.x : q == 1 ? xv.y : q == 2 ? xv.z : xv.w;
                    acc.x += xq * wv.x;
                    acc.y += xq * wv.y;
                    acc.z += xq * wv.z;
                    acc.w += xq * wv.w;
                }
            }
        }
        float4 yv;
        yv.x = acc.x > 0.f ? acc.x : 0.f;
        yv.y = acc.y > 0.f ? acc.y : 0.f;
        yv.z = acc.z > 0.f ? acc.z : 0.f;
        yv.w = acc.w > 0.f ? acc.w : 0.f;
        *(float4*)&ytile[r * 20 + c0 * 4] = yv;
    }
    __syncthreads();
    int items = rcnt * 22;
    for (int it = threadIdx.x; it < items; it += 256) {
        int row = it / 22, col = it - row * 22;
        const float* yr = &ytile[row * 20];
        const float* wc = &sfwT[col * 16];
        float s = sfb[col];
#pragma unroll
        for (int co4 = 0; co4 < 4; ++co4) {
            float4 yv = *(const float4*)&yr[co4 * 4];
            float4 wv = *(const float4*)&wc[co4 * 4];
            s += yv.x * wv.x + yv.y * wv.y + yv.z * wv.z + yv.w * wv.w;
        }
        out[(size_t)base * 22 + it] = s;
    }
}

extern "C" void kernel_launch(void* const* d_in, const int* in_sizes, int n_in,
                              void* d_out, int out_size, void* d_ws, size_t ws_size,
                              hipStream_t stream) {
    const float* x  = (const float*)d_in[0];
    const int*   ei = (const int*)d_in[1];   // int32 (JAX x64 disabled)
    const float* W1 = (const float*)d_in[2];
    const float* b1 = (const float*)d_in[3];
    const float* W2 = (const float*)d_in[4];
    const float* b2 = (const float*)d_in[5];
    const float* cw = (const float*)d_in[6];
    const float* cb = (const float*)d_in[7];
    const float* fw = (const float*)d_in[8];
    const float* fb = (const float*)d_in[9];
    float* out = (float*)d_out;

    int N = in_sizes[0] / 8;       // 100000
    int E = in_sizes[1] / 2;       // 3200000
    const int* src = ei;
    const int* dst = ei + E;
    int NB = (N + BKT_NODES - 1) >> BKT_SHIFT;  // 391

    auto alignB = [](size_t v) { return (v + 1023) & ~(size_t)1023; };
    char* wsb = (char*)d_ws;
    size_t o = 0;
    int* bcnt = (int*)(wsb + o);      o += 2048;
    int* boff = (int*)(wsb + o);      o += 2048;
    int* bcur = (int*)(wsb + o);      o += 2048;
    int* rowstart = (int*)(wsb + o);  o += alignB((size_t)(N + 1) * 4);
    float* dinv = (float*)(wsb + o);  o += alignB((size_t)N * 4);
    int* csr = (int*)(wsb + o);       o += alignB((size_t)E * 4);
    __half2* hx = (__half2*)(wsb + o);  o += alignB((size_t)N * 8 * 2);   // [N][8] fp16
    __half* hw2 = (__half*)(wsb + o);   o += alignB((size_t)N * 32 * 2);  // [N][32] fp16
    float* B = (float*)(wsb + o);     o += (size_t)N * 64 * 4;            // g1, then g2
    int* ebuf = (int*)B;              // dead before B's first write

    hipMemsetAsync(bcnt, 0, (size_t)NB * sizeof(int), stream);
    k_hist<<<(E + 4095) / 4096, 256, 0, stream>>>(dst, bcnt, E, NB);
    k_bscan<<<1, 512, 0, stream>>>(bcnt, boff, bcur, NB, E);
    k_part<<<(E + 8191) / 8192, 1024, 0, stream>>>(src, dst, bcur, ebuf, E, NB);
    k_lsort<<<NB, 256, 0, stream>>>(boff, ebuf, rowstart, dinv, csr, N, NB);

    k_hx<<<(N * 4 + 255) / 256, 256, 0, stream>>>(x, dinv, hx, N * 4);
    k_agg1x<<<(int)(((size_t)N * 4 + 255) / 256), 256, 0, stream>>>(rowstart, csr, dinv, hx, W1, b1, B, N);

    k_gemm2<<<(N + 7) / 8, 256, 0, stream>>>(B, W2, dinv, hw2, N);
    k_aggr32x<<<(int)(((size_t)N * 16 + 255) / 256), 256, 0, stream>>>(rowstart, csr, dinv, hw2, b2, B, N);

    k_head<<<(N - 2 + HROWS - 1) / HROWS, 256, 0, stream>>>(B, cw, cb, fw, fb, out, N - 2);
}

// Round 17
// 195.995 us; speedup vs baseline: 1.2845x; 1.0592x over previous
//
#include <hip/hip_runtime.h>
#include <hip/hip_fp16.h>
#include <math.h>

#define BKT_SHIFT 8
#define BKT_NODES 256
#define HROWS 64

// ---- pass 1: per-bucket histogram (int4-vectorized dst read) ----
__global__ __launch_bounds__(256) void k_hist(const int* __restrict__ dst,
                                              int* __restrict__ bcnt, int E, int NB) {
    __shared__ int lh[512];
    for (int i = threadIdx.x; i < NB; i += 256) lh[i] = 0;
    __syncthreads();
    int base = blockIdx.x * 4096;
    if (base + 4096 <= E) {
        const int4* d4 = (const int4*)(dst + base);
#pragma unroll
        for (int k = 0; k < 4; ++k) {
            int4 v = d4[k * 256 + threadIdx.x];
            atomicAdd(&lh[v.x >> BKT_SHIFT], 1);
            atomicAdd(&lh[v.y >> BKT_SHIFT], 1);
            atomicAdd(&lh[v.z >> BKT_SHIFT], 1);
            atomicAdd(&lh[v.w >> BKT_SHIFT], 1);
        }
    } else {
        for (int k = 0; k < 16; ++k) {
            int i = base + k * 256 + threadIdx.x;
            if (i < E) atomicAdd(&lh[dst[i] >> BKT_SHIFT], 1);
        }
    }
    __syncthreads();
    for (int i = threadIdx.x; i < NB; i += 256)
        if (lh[i]) atomicAdd(&bcnt[i], lh[i]);
}

// ---- exclusive scan over NB buckets (single block) ----
__global__ __launch_bounds__(512) void k_bscan(const int* __restrict__ bc,
                                               int* __restrict__ boff,
                                               int* __restrict__ bcur, int NB, int E) {
    __shared__ int s[512];
    __shared__ int carry;
    if (threadIdx.x == 0) carry = 0;
    __syncthreads();
    for (int base = 0; base < NB; base += 512) {
        int i = base + threadIdx.x;
        int v = (i < NB) ? bc[i] : 0;
        s[threadIdx.x] = v;
        __syncthreads();
        for (int off = 1; off < 512; off <<= 1) {
            int t = (threadIdx.x >= off) ? s[threadIdx.x - off] : 0;
            __syncthreads();
            s[threadIdx.x] += t;
            __syncthreads();
        }
        if (i < NB) {
            int ex = carry + s[threadIdx.x] - v;
            boff[i] = ex;
            bcur[i] = ex;
        }
        __syncthreads();
        if (threadIdx.x == 0) carry += s[511];
        __syncthreads();
    }
    if (threadIdx.x == 0) boff[NB] = E;
}

// ---- pass 2: partition edges; record = (d&255)<<24 | src ----
__global__ __launch_bounds__(1024) void k_part(const int* __restrict__ src,
                                               const int* __restrict__ dst,
                                               int* __restrict__ bcur,
                                               int* __restrict__ ebuf, int E, int NB) {
    __shared__ int lh[512];
    for (int i = threadIdx.x; i < NB; i += 1024) lh[i] = 0;
    __syncthreads();
    int base = blockIdx.x * 8192;
    if (base + 8192 <= E) {
        const int4* d4 = (const int4*)(dst + base);
#pragma unroll
        for (int k = 0; k < 2; ++k) {
            int4 v = d4[k * 1024 + threadIdx.x];
            atomicAdd(&lh[v.x >> BKT_SHIFT], 1);
            atomicAdd(&lh[v.y >> BKT_SHIFT], 1);
            atomicAdd(&lh[v.z >> BKT_SHIFT], 1);
            atomicAdd(&lh[v.w >> BKT_SHIFT], 1);
        }
    } else {
        for (int k = 0; k < 8; ++k) {
            int i = base + k * 1024 + threadIdx.x;
            if (i < E) atomicAdd(&lh[dst[i] >> BKT_SHIFT], 1);
        }
    }
    __syncthreads();
    for (int t = threadIdx.x; t < NB; t += 1024) {
        int c = lh[t];
        lh[t] = c ? atomicAdd(&bcur[t], c) : 0;
    }
    __syncthreads();
    if (base + 8192 <= E) {
        const int4* d4 = (const int4*)(dst + base);
        const int4* s4 = (const int4*)(src + base);
#pragma unroll
        for (int k = 0; k < 2; ++k) {
            int4 dv = d4[k * 1024 + threadIdx.x];
            int4 sv = s4[k * 1024 + threadIdx.x];
            int p;
            p = atomicAdd(&lh[dv.x >> BKT_SHIFT], 1); ebuf[p] = ((dv.x & 255) << 24) | sv.x;
            p = atomicAdd(&lh[dv.y >> BKT_SHIFT], 1); ebuf[p] = ((dv.y & 255) << 24) | sv.y;
            p = atomicAdd(&lh[dv.z >> BKT_SHIFT], 1); ebuf[p] = ((dv.z & 255) << 24) | sv.z;
            p = atomicAdd(&lh[dv.w >> BKT_SHIFT], 1); ebuf[p] = ((dv.w & 255) << 24) | sv.w;
        }
    } else {
        for (int k = 0; k < 8; ++k) {
            int i = base + k * 1024 + threadIdx.x;
            if (i < E) {
                int d = dst[i];
                int p = atomicAdd(&lh[d >> BKT_SHIFT], 1);
                ebuf[p] = ((d & 255) << 24) | src[i];
            }
        }
    }
}

// ---- pass 3: counting sort + dinv + hx (fused) ----
__global__ __launch_bounds__(256) void k_lsort(const int* __restrict__ boff,
                                               const int* __restrict__ ebuf,
                                               const float* __restrict__ x,
                                               int* __restrict__ rowstart,
                                               float* __restrict__ dinv,
                                               __half2* __restrict__ hx,
                                               int* __restrict__ csr, int n, int NB) {
    __shared__ int off[256];
    __shared__ int cnt[256];
    int b = blockIdx.x;
    int start = boff[b], end = boff[b + 1];
    cnt[threadIdx.x] = 0;
    __syncthreads();
    for (int i = start + threadIdx.x; i < end; i += 256)
        atomicAdd(&cnt[((unsigned)ebuf[i]) >> 24], 1);
    __syncthreads();
    int v = cnt[threadIdx.x];
    off[threadIdx.x] = v;
    __syncthreads();
    for (int o = 1; o < 256; o <<= 1) {
        int t = (threadIdx.x >= o) ? off[threadIdx.x - o] : 0;
        __syncthreads();
        off[threadIdx.x] += t;
        __syncthreads();
    }
    int excl = off[threadIdx.x] - v;
    int node = (b << BKT_SHIFT) + threadIdx.x;
    if (node < n) {
        rowstart[node] = start + excl;
        float dv = rsqrtf((float)v + 1.0f);  // +1 = self-loop
        dinv[node] = dv;
        const float4* xp = (const float4*)(x + (size_t)node * 8);
        float4 a = xp[0], c = xp[1];
        __half2* hp = hx + (size_t)node * 4;
        hp[0] = __floats2half2_rn(a.x * dv, a.y * dv);
        hp[1] = __floats2half2_rn(a.z * dv, a.w * dv);
        hp[2] = __floats2half2_rn(c.x * dv, c.y * dv);
        hp[3] = __floats2half2_rn(c.z * dv, c.w * dv);
    }
    __syncthreads();
    off[threadIdx.x] = excl;  // reuse as cursor
    __syncthreads();
    for (int i = start + threadIdx.x; i < end; i += 256) {
        int rec = ebuf[i];
        int d = ((unsigned)rec) >> 24;
        int pos = atomicAdd(&off[d], 1);
        csr[start + pos] = rec & 0xFFFFFF;
    }
    if (b == NB - 1 && threadIdx.x == 0) rowstart[n] = end;
}

// ---- fused layer-1: 16 nodes/wave, 4 lanes/node, 16-deep predicated gather,
//      quad-allgather, each lane computes 16 of 64 outputs ----
__global__ __launch_bounds__(256) void k_agg1p(const int* __restrict__ rs, const int* __restrict__ csr,
                                               const float* __restrict__ dinv, const __half2* __restrict__ hx,
                                               const float* __restrict__ W1, const float* __restrict__ bias,
                                               float* __restrict__ g, int n) {
    __shared__ float w[512];   // W1 [8][64]
    __shared__ float sb[64];
    for (int i = threadIdx.x; i < 512; i += 256) w[i] = W1[i];
    if (threadIdx.x < 64) sb[threadIdx.x] = bias[threadIdx.x];
    __syncthreads();
    int wid = (blockIdx.x * 256 + threadIdx.x) >> 2;   // node
    if (wid >= n) return;
    int jp = threadIdx.x & 3;          // half2 index (feats 2jp, 2jp+1)
    int start = rs[wid], end = rs[wid + 1];
    float ax = 0.f, ay = 0.f;
    for (int i = start; i < end; i += 16) {
        int idx[16];
        float msk[16];
#pragma unroll
        for (int k = 0; k < 16; ++k) {
            int ii = i + k;
            bool ok = ii < end;
            idx[k] = ok ? csr[ii] : wid;
            msk[k] = ok ? 1.f : 0.f;
        }
        float2 f[16];
#pragma unroll
        for (int k = 0; k < 16; ++k)
            f[k] = __half22float2(hx[((size_t)idx[k] << 2) + jp]);
#pragma unroll
        for (int k = 0; k < 16; ++k) {
            ax = fmaf(msk[k], f[k].x, ax);
            ay = fmaf(msk[k], f[k].y, ay);
        }
    }
    {   // self-loop row
        float2 f = __half22float2(hx[((size_t)wid << 2) + jp]);
        ax += f.x; ay += f.y;
    }
    // quad allgather
    float bx = __shfl_xor(ax, 1), by = __shfl_xor(ay, 1);
    float cx = __shfl_xor(ax, 2), cy = __shfl_xor(ay, 2);
    float dx = __shfl_xor(bx, 2), dy = __shfl_xor(by, 2);
    float dv = dinv[wid];
    int fb = jp * 16;
    const float* r0 = &w[(2 * jp) * 64 + fb];          const float* r1 = r0 + 64;
    const float* r2 = &w[(2 * (jp ^ 1)) * 64 + fb];    const float* r3 = r2 + 64;
    const float* r4 = &w[(2 * (jp ^ 2)) * 64 + fb];    const float* r5 = r4 + 64;
    const float* r6 = &w[(2 * (jp ^ 3)) * 64 + fb];    const float* r7 = r6 + 64;
    float* gout = g + (size_t)wid * 64 + fb;
    const float* sbp = &sb[fb];
#pragma unroll
    for (int m4 = 0; m4 < 4; ++m4) {
        float4 wa = *(const float4*)&r0[m4 * 4];
        float4 wb = *(const float4*)&r1[m4 * 4];
        float4 wc = *(const float4*)&r2[m4 * 4];
        float4 wd = *(const float4*)&r3[m4 * 4];
        float4 we = *(const float4*)&r4[m4 * 4];
        float4 wf = *(const float4*)&r5[m4 * 4];
        float4 wg = *(const float4*)&r6[m4 * 4];
        float4 wh = *(const float4*)&r7[m4 * 4];
        float4 o;
        o.x = dv * (ax * wa.x + ay * wb.x + bx * wc.x + by * wd.x + cx * we.x + cy * wf.x + dx * wg.x + dy * wh.x) + sbp[m4 * 4 + 0];
        o.y = dv * (ax * wa.y + ay * wb.y + bx * wc.y + by * wd.y + cx * we.y + cy * wf.y + dx * wg.y + dy * wh.y) + sbp[m4 * 4 + 1];
        o.z = dv * (ax * wa.z + ay * wb.z + bx * wc.z + by * wd.z + cx * we.z + cy * wf.z + dx * wg.z + dy * wh.z) + sbp[m4 * 4 + 2];
        o.w = dv * (ax * wa.w + ay * wb.w + bx * wc.w + by * wd.w + cx * we.w + cy * wf.w + dx * wg.w + dy * wh.w) + sbp[m4 * 4 + 3];
        o.x = o.x > 0.f ? o.x : expm1f(o.x);
        o.y = o.y > 0.f ? o.y : expm1f(o.y);
        o.z = o.z > 0.f ? o.z : expm1f(o.z);
        o.w = o.w > 0.f ? o.w : expm1f(o.w);
        *(float4*)&gout[m4 * 4] = o;
    }
}

// ---- layer-2: 4 nodes/wave, 16 lanes/node, 16-deep predicated gather ----
__global__ __launch_bounds__(256) void k_aggr32p(const int* __restrict__ rs, const int* __restrict__ csr,
                                                 const float* __restrict__ dinv, const __half* __restrict__ hw,
                                                 const float* __restrict__ bias, float* __restrict__ g, int n) {
    int wid = (blockIdx.x * 256 + threadIdx.x) >> 4;
    if (wid >= n) return;
    int j = threadIdx.x & 15;           // feature pair (feats 2j, 2j+1)
    int start = rs[wid], end = rs[wid + 1];
    const __half2* hp = (const __half2*)hw;
    float ax = 0.f, ay = 0.f;
    for (int i = start; i < end; i += 16) {
        int idx[16];
        float msk[16];
#pragma unroll
        for (int k = 0; k < 16; ++k) {
            int ii = i + k;
            bool ok = ii < end;
            idx[k] = ok ? csr[ii] : wid;
            msk[k] = ok ? 1.f : 0.f;
        }
        float2 f[16];
#pragma unroll
        for (int k = 0; k < 16; ++k)
            f[k] = __half22float2(hp[((size_t)idx[k] << 4) + j]);
#pragma unroll
        for (int k = 0; k < 16; ++k) {
            ax = fmaf(msk[k], f[k].x, ax);
            ay = fmaf(msk[k], f[k].y, ay);
        }
    }
    float dv = dinv[wid];
    float2 fs = __half22float2(hp[((size_t)wid << 4) + j]);
    float2 bb = ((const float2*)bias)[j];
    float vx = dv * (ax + fs.x) + bb.x;
    float vy = dv * (ay + fs.y) + bb.y;
    float2 r;
    r.x = vx > 0.f ? vx : expm1f(vx);
    r.y = vy > 0.f ? vy : expm1f(vy);
    ((float2*)(g + ((size_t)wid << 5)))[j] = r;
}

// ---- hw2 = fp16((g1 @ W2) * dinv)  (64 -> 32) ----
__global__ __launch_bounds__(256) void k_gemm2(const float* __restrict__ g1, const float* __restrict__ W2,
                                               const float* __restrict__ dinv, __half* __restrict__ hw2, int n) {
    __shared__ float w[2048];
    __shared__ float xs[512];
    for (int i = threadIdx.x; i < 2048; i += 256) w[i] = W2[i];
    int nb = blockIdx.x * 8;
    for (int i = threadIdx.x; i < 512; i += 256) {
        int r = i >> 6, c = i & 63;
        int node = nb + r;
        xs[i] = (node < n) ? g1[(size_t)node * 64 + c] : 0.f;
    }
    __syncthreads();
    int node = nb + (threadIdx.x >> 5);
    int j = threadIdx.x & 31;
    if (node >= n) return;
    const float* xr = &xs[(threadIdx.x >> 5) << 6];
    float s = 0.f;
#pragma unroll
    for (int k = 0; k < 64; ++k) s += xr[k] * w[k * 32 + j];
    hw2[(size_t)node * 32 + j] = __float2half_rn(s * dinv[node]);
}

// ---- cooperative head: conv1d(32->16,k=3)+relu+fc(16->22), 64 rows/block ----
__global__ __launch_bounds__(256) void k_head(const float* __restrict__ g2, const float* __restrict__ cw,
                                              const float* __restrict__ cb, const float* __restrict__ fw,
                                              const float* __restrict__ fb, float* __restrict__ out,
                                              int nrows) {
    __shared__ float tile[(HROWS + 2) * 36];
    __shared__ float scwT[96 * 16];
    __shared__ float ytile[HROWS * 20];
    __shared__ float sfwT[22 * 16];
    __shared__ float scb[16], sfb[22];
    int base = blockIdx.x * HROWS;
    int rcnt = nrows - base; if (rcnt > HROWS) rcnt = HROWS;
    for (int i = threadIdx.x; i < 1536; i += 256) {
        int co = i / 96, rem = i - co * 96;
        scwT[rem * 16 + co] = cw[i];
    }
    for (int i = threadIdx.x; i < 352; i += 256) {
        int co = i / 22, col = i - co * 22;
        sfwT[col * 16 + co] = fw[i];
    }
    if (threadIdx.x < 16) scb[threadIdx.x] = cb[threadIdx.x];
    if (threadIdx.x < 22) sfb[threadIdx.x] = fb[threadIdx.x];
    int nload4 = (rcnt + 2) * 8;
    for (int i = threadIdx.x; i < nload4; i += 256) {
        int r = i >> 3, c4 = i & 7;
        float4 v = *(const float4*)(g2 + (size_t)(base + r) * 32 + c4 * 4);
        *(float4*)&tile[r * 36 + c4 * 4] = v;
    }
    __syncthreads();
    int r = threadIdx.x >> 2;
    int c0 = threadIdx.x & 3;
    if (r < rcnt) {
        float4 acc = { scb[c0 * 4], scb[c0 * 4 + 1], scb[c0 * 4 + 2], scb[c0 * 4 + 3] };
#pragma unroll
        for (int k = 0; k < 3; ++k) {
            const float* tr = &tile[(r + k) * 36];
#pragma unroll
            for (int ci4 = 0; ci4 < 8; ++ci4) {
                float4 xv = *(const float4*)&tr[ci4 * 4];
#pragma unroll
                for (int q = 0; q < 4; ++q) {
                    int ci = ci4 * 4 + q;
                    float4 wv = *(const float4*)&scwT[(ci * 3 + k) * 16 + c0 * 4];
                    float xq = q == 0 ? xv.x : q == 1 ? xv.y : q == 2 ? xv.z : xv.w;
                    acc.x += xq * wv.x;
                    acc.y += xq * wv.y;
                    acc.z += xq * wv.z;
                    acc.w += xq * wv.w;
                }
            }
        }
        float4 yv;
        yv.x = acc.x > 0.f ? acc.x : 0.f;
        yv.y = acc.y > 0.f ? acc.y : 0.f;
        yv.z = acc.z > 0.f ? acc.z : 0.f;
        yv.w = acc.w > 0.f ? acc.w : 0.f;
        *(float4*)&ytile[r * 20 + c0 * 4] = yv;
    }
    __syncthreads();
    int items = rcnt * 22;
    for (int it = threadIdx.x; it < items; it += 256) {
        int row = it / 22, col = it - row * 22;
        const float* yr = &ytile[row * 20];
        const float* wc = &sfwT[col * 16];
        float s = sfb[col];
#pragma unroll
        for (int co4 = 0; co4 < 4; ++co4) {
            float4 yv = *(const float4*)&yr[co4 * 4];
            float4 wv = *(const float4*)&wc[co4 * 4];
            s += yv.x * wv.x + yv.y * wv.y + yv.z * wv.z + yv.w * wv.w;
        }
        out[(size_t)base * 22 + it] = s;
    }
}

extern "C" void kernel_launch(void* const* d_in, const int* in_sizes, int n_in,
                              void* d_out, int out_size, void* d_ws, size_t ws_size,
                              hipStream_t stream) {
    const float* x  = (const float*)d_in[0];
    const int*   ei = (const int*)d_in[1];   // int32 (JAX x64 disabled)
    const float* W1 = (const float*)d_in[2];
    const float* b1 = (const float*)d_in[3];
    const float* W2 = (const float*)d_in[4];
    const float* b2 = (const float*)d_in[5];
    const float* cw = (const float*)d_in[6];
    const float* cb = (const float*)d_in[7];
    const float* fw = (const float*)d_in[8];
    const float* fb = (const float*)d_in[9];
    float* out = (float*)d_out;

    int N = in_sizes[0] / 8;       // 100000
    int E = in_sizes[1] / 2;       // 3200000
    const int* src = ei;
    const int* dst = ei + E;
    int NB = (N + BKT_NODES - 1) >> BKT_SHIFT;  // 391

    auto alignB = [](size_t v) { return (v + 1023) & ~(size_t)1023; };
    char* wsb = (char*)d_ws;
    size_t o = 0;
    int* bcnt = (int*)(wsb + o);      o += 2048;
    int* boff = (int*)(wsb + o);      o += 2048;
    int* bcur = (int*)(wsb + o);      o += 2048;
    int* rowstart = (int*)(wsb + o);  o += alignB((size_t)(N + 1) * 4);
    float* dinv = (float*)(wsb + o);  o += alignB((size_t)N * 4);
    int* csr = (int*)(wsb + o);       o += alignB((size_t)E * 4 + 256);
    __half2* hx = (__half2*)(wsb + o);  o += alignB((size_t)N * 8 * 2);   // [N][8] fp16
    __half* hw2 = (__half*)(wsb + o);   o += alignB((size_t)N * 32 * 2);  // [N][32] fp16
    float* B = (float*)(wsb + o);     o += (size_t)N * 64 * 4;            // g1, then g2
    int* ebuf = (int*)B;              // dead before B's first write

    hipMemsetAsync(bcnt, 0, (size_t)NB * sizeof(int), stream);
    k_hist<<<(E + 4095) / 4096, 256, 0, stream>>>(dst, bcnt, E, NB);
    k_bscan<<<1, 512, 0, stream>>>(bcnt, boff, bcur, NB, E);
    k_part<<<(E + 8191) / 8192, 1024, 0, stream>>>(src, dst, bcur, ebuf, E, NB);
    k_lsort<<<NB, 256, 0, stream>>>(boff, ebuf, x, rowstart, dinv, hx, csr, N, NB);

    k_agg1p<<<(int)(((size_t)N * 4 + 255) / 256), 256, 0, stream>>>(rowstart, csr, dinv, hx, W1, b1, B, N);

    k_gemm2<<<(N + 7) / 8, 256, 0, stream>>>(B, W2, dinv, hw2, N);
    k_aggr32p<<<(int)(((size_t)N * 16 + 255) / 256), 256, 0, stream>>>(rowstart, csr, dinv, hw2, b2, B, N);

    k_head<<<(N - 2 + HROWS - 1) / HROWS, 256, 0, stream>>>(B, cw, cb, fw, fb, out, N - 2);
}

// Round 18
// 183.817 us; speedup vs baseline: 1.3696x; 1.0662x over previous
//
#include <hip/hip_runtime.h>
#include <hip/hip_fp16.h>
#include <math.h>

#define BKT_SHIFT 8
#define BKT_NODES 256
#define HROWS 64

// ---- pass 1: per-bucket histogram (int4-vectorized dst read) ----
__global__ __launch_bounds__(256) void k_hist(const int* __restrict__ dst,
                                              int* __restrict__ bcnt, int E, int NB) {
    __shared__ int lh[512];
    for (int i = threadIdx.x; i < NB; i += 256) lh[i] = 0;
    __syncthreads();
    int base = blockIdx.x * 4096;
    if (base + 4096 <= E) {
        const int4* d4 = (const int4*)(dst + base);
#pragma unroll
        for (int k = 0; k < 4; ++k) {
            int4 v = d4[k * 256 + threadIdx.x];
            atomicAdd(&lh[v.x >> BKT_SHIFT], 1);
            atomicAdd(&lh[v.y >> BKT_SHIFT], 1);
            atomicAdd(&lh[v.z >> BKT_SHIFT], 1);
            atomicAdd(&lh[v.w >> BKT_SHIFT], 1);
        }
    } else {
        for (int k = 0; k < 16; ++k) {
            int i = base + k * 256 + threadIdx.x;
            if (i < E) atomicAdd(&lh[dst[i] >> BKT_SHIFT], 1);
        }
    }
    __syncthreads();
    for (int i = threadIdx.x; i < NB; i += 256)
        if (lh[i]) atomicAdd(&bcnt[i], lh[i]);
}

// ---- exclusive scan over NB buckets (single block) ----
__global__ __launch_bounds__(512) void k_bscan(const int* __restrict__ bc,
                                               int* __restrict__ boff,
                                               int* __restrict__ bcur, int NB, int E) {
    __shared__ int s[512];
    __shared__ int carry;
    if (threadIdx.x == 0) carry = 0;
    __syncthreads();
    for (int base = 0; base < NB; base += 512) {
        int i = base + threadIdx.x;
        int v = (i < NB) ? bc[i] : 0;
        s[threadIdx.x] = v;
        __syncthreads();
        for (int off = 1; off < 512; off <<= 1) {
            int t = (threadIdx.x >= off) ? s[threadIdx.x - off] : 0;
            __syncthreads();
            s[threadIdx.x] += t;
            __syncthreads();
        }
        if (i < NB) {
            int ex = carry + s[threadIdx.x] - v;
            boff[i] = ex;
            bcur[i] = ex;
        }
        __syncthreads();
        if (threadIdx.x == 0) carry += s[511];
        __syncthreads();
    }
    if (threadIdx.x == 0) boff[NB] = E;
}

// ---- pass 2: partition edges; record = (d&255)<<24 | src ----
__global__ __launch_bounds__(1024) void k_part(const int* __restrict__ src,
                                               const int* __restrict__ dst,
                                               int* __restrict__ bcur,
                                               int* __restrict__ ebuf, int E, int NB) {
    __shared__ int lh[512];
    for (int i = threadIdx.x; i < NB; i += 1024) lh[i] = 0;
    __syncthreads();
    int base = blockIdx.x * 8192;
    if (base + 8192 <= E) {
        const int4* d4 = (const int4*)(dst + base);
#pragma unroll
        for (int k = 0; k < 2; ++k) {
            int4 v = d4[k * 1024 + threadIdx.x];
            atomicAdd(&lh[v.x >> BKT_SHIFT], 1);
            atomicAdd(&lh[v.y >> BKT_SHIFT], 1);
            atomicAdd(&lh[v.z >> BKT_SHIFT], 1);
            atomicAdd(&lh[v.w >> BKT_SHIFT], 1);
        }
    } else {
        for (int k = 0; k < 8; ++k) {
            int i = base + k * 1024 + threadIdx.x;
            if (i < E) atomicAdd(&lh[dst[i] >> BKT_SHIFT], 1);
        }
    }
    __syncthreads();
    for (int t = threadIdx.x; t < NB; t += 1024) {
        int c = lh[t];
        lh[t] = c ? atomicAdd(&bcur[t], c) : 0;
    }
    __syncthreads();
    if (base + 8192 <= E) {
        const int4* d4 = (const int4*)(dst + base);
        const int4* s4 = (const int4*)(src + base);
#pragma unroll
        for (int k = 0; k < 2; ++k) {
            int4 dv = d4[k * 1024 + threadIdx.x];
            int4 sv = s4[k * 1024 + threadIdx.x];
            int p;
            p = atomicAdd(&lh[dv.x >> BKT_SHIFT], 1); ebuf[p] = ((dv.x & 255) << 24) | sv.x;
            p = atomicAdd(&lh[dv.y >> BKT_SHIFT], 1); ebuf[p] = ((dv.y & 255) << 24) | sv.y;
            p = atomicAdd(&lh[dv.z >> BKT_SHIFT], 1); ebuf[p] = ((dv.z & 255) << 24) | sv.z;
            p = atomicAdd(&lh[dv.w >> BKT_SHIFT], 1); ebuf[p] = ((dv.w & 255) << 24) | sv.w;
        }
    } else {
        for (int k = 0; k < 8; ++k) {
            int i = base + k * 1024 + threadIdx.x;
            if (i < E) {
                int d = dst[i];
                int p = atomicAdd(&lh[d >> BKT_SHIFT], 1);
                ebuf[p] = ((d & 255) << 24) | src[i];
            }
        }
    }
}

// ---- pass 3: counting sort + dinv + hx (fused) ----
__global__ __launch_bounds__(256) void k_lsort(const int* __restrict__ boff,
                                               const int* __restrict__ ebuf,
                                               const float* __restrict__ x,
                                               int* __restrict__ rowstart,
                                               float* __restrict__ dinv,
                                               __half2* __restrict__ hx,
                                               int* __restrict__ csr, int n, int NB) {
    __shared__ int off[256];
    __shared__ int cnt[256];
    int b = blockIdx.x;
    int start = boff[b], end = boff[b + 1];
    cnt[threadIdx.x] = 0;
    __syncthreads();
    for (int i = start + threadIdx.x; i < end; i += 256)
        atomicAdd(&cnt[((unsigned)ebuf[i]) >> 24], 1);
    __syncthreads();
    int v = cnt[threadIdx.x];
    off[threadIdx.x] = v;
    __syncthreads();
    for (int o = 1; o < 256; o <<= 1) {
        int t = (threadIdx.x >= o) ? off[threadIdx.x - o] : 0;
        __syncthreads();
        off[threadIdx.x] += t;
        __syncthreads();
    }
    int excl = off[threadIdx.x] - v;
    int node = (b << BKT_SHIFT) + threadIdx.x;
    if (node < n) {
        rowstart[node] = start + excl;
        float dv = rsqrtf((float)v + 1.0f);  // +1 = self-loop
        dinv[node] = dv;
        const float4* xp = (const float4*)(x + (size_t)node * 8);
        float4 a = xp[0], c = xp[1];
        __half2* hp = hx + (size_t)node * 4;
        hp[0] = __floats2half2_rn(a.x * dv, a.y * dv);
        hp[1] = __floats2half2_rn(a.z * dv, a.w * dv);
        hp[2] = __floats2half2_rn(c.x * dv, c.y * dv);
        hp[3] = __floats2half2_rn(c.z * dv, c.w * dv);
    }
    __syncthreads();
    off[threadIdx.x] = excl;  // reuse as cursor
    __syncthreads();
    for (int i = start + threadIdx.x; i < end; i += 256) {
        int rec = ebuf[i];
        int d = ((unsigned)rec) >> 24;
        int pos = atomicAdd(&off[d], 1);
        csr[start + pos] = rec & 0xFFFFFF;
    }
    if (b == NB - 1 && threadIdx.x == 0) rowstart[n] = end;
}

// ---- fused layer-1 + gemm2: 16 nodes/wave, 4 lanes/node, 16-deep gather,
//      quad-allgather -> g1 (in regs) -> @W2 -> butterfly reduce-scatter -> hw2 fp16 ----
__global__ __launch_bounds__(256) void k_agg1g(const int* __restrict__ rs, const int* __restrict__ csr,
                                               const float* __restrict__ dinv, const __half2* __restrict__ hx,
                                               const float* __restrict__ W1, const float* __restrict__ bias,
                                               const float* __restrict__ W2, __half* __restrict__ hw2, int n) {
    __shared__ float w[512];    // W1 [8][64]
    __shared__ float sb[64];
    __shared__ float w2s[64 * 36];  // W2 [64][32] padded to stride 36 (16B-aligned rows)
    for (int i = threadIdx.x; i < 512; i += 256) w[i] = W1[i];
    if (threadIdx.x < 64) sb[threadIdx.x] = bias[threadIdx.x];
    for (int i = threadIdx.x; i < 2048; i += 256) {
        int r = i >> 5, c = i & 31;
        w2s[r * 36 + c] = W2[i];
    }
    __syncthreads();
    int wid = (blockIdx.x * 256 + threadIdx.x) >> 2;   // node
    if (wid >= n) return;
    int jp = threadIdx.x & 3;          // half2 index (feats 2jp, 2jp+1)
    int start = rs[wid], end = rs[wid + 1];
    float ax = 0.f, ay = 0.f;
    for (int i = start; i < end; i += 16) {
        int idx[16];
        float msk[16];
#pragma unroll
        for (int k = 0; k < 16; ++k) {
            int ii = i + k;
            bool ok = ii < end;
            idx[k] = ok ? csr[ii] : wid;
            msk[k] = ok ? 1.f : 0.f;
        }
        float2 f[16];
#pragma unroll
        for (int k = 0; k < 16; ++k)
            f[k] = __half22float2(hx[((size_t)idx[k] << 2) + jp]);
#pragma unroll
        for (int k = 0; k < 16; ++k) {
            ax = fmaf(msk[k], f[k].x, ax);
            ay = fmaf(msk[k], f[k].y, ay);
        }
    }
    {   // self-loop row
        float2 f = __half22float2(hx[((size_t)wid << 2) + jp]);
        ax += f.x; ay += f.y;
    }
    // quad allgather of aggregated input feats
    float bx = __shfl_xor(ax, 1), by = __shfl_xor(ay, 1);
    float cx = __shfl_xor(ax, 2), cy = __shfl_xor(ay, 2);
    float dx = __shfl_xor(bx, 2), dy = __shfl_xor(by, 2);
    float dv = dinv[wid];
    int fb = jp * 16;   // this lane's g1 slice [fb, fb+16)
    const float* r0 = &w[(2 * jp) * 64 + fb];          const float* r1 = r0 + 64;
    const float* r2 = &w[(2 * (jp ^ 1)) * 64 + fb];    const float* r3 = r2 + 64;
    const float* r4 = &w[(2 * (jp ^ 2)) * 64 + fb];    const float* r5 = r4 + 64;
    const float* r6 = &w[(2 * (jp ^ 3)) * 64 + fb];    const float* r7 = r6 + 64;
    const float* sbp = &sb[fb];
    float4 o4[4];
#pragma unroll
    for (int m4 = 0; m4 < 4; ++m4) {
        float4 wa = *(const float4*)&r0[m4 * 4];
        float4 wb = *(const float4*)&r1[m4 * 4];
        float4 wc = *(const float4*)&r2[m4 * 4];
        float4 wd = *(const float4*)&r3[m4 * 4];
        float4 we = *(const float4*)&r4[m4 * 4];
        float4 wf = *(const float4*)&r5[m4 * 4];
        float4 wg = *(const float4*)&r6[m4 * 4];
        float4 wh = *(const float4*)&r7[m4 * 4];
        float4 o;
        o.x = dv * (ax * wa.x + ay * wb.x + bx * wc.x + by * wd.x + cx * we.x + cy * wf.x + dx * wg.x + dy * wh.x) + sbp[m4 * 4 + 0];
        o.y = dv * (ax * wa.y + ay * wb.y + bx * wc.y + by * wd.y + cx * we.y + cy * wf.y + dx * wg.y + dy * wh.y) + sbp[m4 * 4 + 1];
        o.z = dv * (ax * wa.z + ay * wb.z + bx * wc.z + by * wd.z + cx * we.z + cy * wf.z + dx * wg.z + dy * wh.z) + sbp[m4 * 4 + 2];
        o.w = dv * (ax * wa.w + ay * wb.w + bx * wc.w + by * wd.w + cx * we.w + cy * wf.w + dx * wg.w + dy * wh.w) + sbp[m4 * 4 + 3];
        o.x = o.x > 0.f ? o.x : expm1f(o.x);
        o.y = o.y > 0.f ? o.y : expm1f(o.y);
        o.z = o.z > 0.f ? o.z : expm1f(o.z);
        o.w = o.w > 0.f ? o.w : expm1f(o.w);
        o4[m4] = o;
    }
    // second GEMM: partial[j] over this lane's 16 g1 values, j = 0..31
    float4 acc[8];
#pragma unroll
    for (int j4 = 0; j4 < 8; ++j4) acc[j4] = make_float4(0.f, 0.f, 0.f, 0.f);
#pragma unroll
    for (int m4 = 0; m4 < 4; ++m4) {
        float4 ov = o4[m4];
#pragma unroll
        for (int q = 0; q < 4; ++q) {
            float om = q == 0 ? ov.x : q == 1 ? ov.y : q == 2 ? ov.z : ov.w;
            const float4* wr = (const float4*)&w2s[(fb + m4 * 4 + q) * 36];
#pragma unroll
            for (int j4 = 0; j4 < 8; ++j4) {
                float4 wv = wr[j4];
                acc[j4].x = fmaf(om, wv.x, acc[j4].x);
                acc[j4].y = fmaf(om, wv.y, acc[j4].y);
                acc[j4].z = fmaf(om, wv.z, acc[j4].z);
                acc[j4].w = fmaf(om, wv.w, acc[j4].w);
            }
        }
    }
    // butterfly reduce-scatter across the 4 lanes (static indexing only)
    bool hi1 = (jp & 1) != 0;
    float4 keep1[4];
#pragma unroll
    for (int i = 0; i < 4; ++i) {
        float4 lo = acc[i], hi = acc[i + 4];
        float4 mine, send;
        mine.x = hi1 ? hi.x : lo.x;  send.x = hi1 ? lo.x : hi.x;
        mine.y = hi1 ? hi.y : lo.y;  send.y = hi1 ? lo.y : hi.y;
        mine.z = hi1 ? hi.z : lo.z;  send.z = hi1 ? lo.z : hi.z;
        mine.w = hi1 ? hi.w : lo.w;  send.w = hi1 ? lo.w : hi.w;
        mine.x += __shfl_xor(send.x, 1);
        mine.y += __shfl_xor(send.y, 1);
        mine.z += __shfl_xor(send.z, 1);
        mine.w += __shfl_xor(send.w, 1);
        keep1[i] = mine;
    }
    bool hi2 = (jp & 2) != 0;
    float4 fin[2];
#pragma unroll
    for (int i = 0; i < 2; ++i) {
        float4 lo = keep1[i], hi = keep1[i + 2];
        float4 mine, send;
        mine.x = hi2 ? hi.x : lo.x;  send.x = hi2 ? lo.x : hi.x;
        mine.y = hi2 ? hi.y : lo.y;  send.y = hi2 ? lo.y : hi.y;
        mine.z = hi2 ? hi.z : lo.z;  send.z = hi2 ? lo.z : hi.z;
        mine.w = hi2 ? hi.w : lo.w;  send.w = hi2 ? lo.w : hi.w;
        mine.x += __shfl_xor(send.x, 2);
        mine.y += __shfl_xor(send.y, 2);
        mine.z += __shfl_xor(send.z, 2);
        mine.w += __shfl_xor(send.w, 2);
        fin[i] = mine;
    }
    // lane jp holds finished j in [jb, jb+8), jb = (jp&1)*16 + (jp&2)*4
    int jb = (jp & 1) * 16 + (jp & 2) * 4;
    __half2 h01 = __floats2half2_rn(fin[0].x * dv, fin[0].y * dv);
    __half2 h23 = __floats2half2_rn(fin[0].z * dv, fin[0].w * dv);
    __half2 h45 = __floats2half2_rn(fin[1].x * dv, fin[1].y * dv);
    __half2 h67 = __floats2half2_rn(fin[1].z * dv, fin[1].w * dv);
    uint4 u;
    u.x = *(unsigned*)&h01; u.y = *(unsigned*)&h23;
    u.z = *(unsigned*)&h45; u.w = *(unsigned*)&h67;
    *(uint4*)((char*)hw2 + (size_t)wid * 64 + jb * 2) = u;
}

// ---- layer-2: 4 nodes/wave, 16 lanes/node, 16-deep predicated gather ----
__global__ __launch_bounds__(256) void k_aggr32p(const int* __restrict__ rs, const int* __restrict__ csr,
                                                 const float* __restrict__ dinv, const __half* __restrict__ hw,
                                                 const float* __restrict__ bias, float* __restrict__ g, int n) {
    int wid = (blockIdx.x * 256 + threadIdx.x) >> 4;
    if (wid >= n) return;
    int j = threadIdx.x & 15;           // feature pair (feats 2j, 2j+1)
    int start = rs[wid], end = rs[wid + 1];
    const __half2* hp = (const __half2*)hw;
    float ax = 0.f, ay = 0.f;
    for (int i = start; i < end; i += 16) {
        int idx[16];
        float msk[16];
#pragma unroll
        for (int k = 0; k < 16; ++k) {
            int ii = i + k;
            bool ok = ii < end;
            idx[k] = ok ? csr[ii] : wid;
            msk[k] = ok ? 1.f : 0.f;
        }
        float2 f[16];
#pragma unroll
        for (int k = 0; k < 16; ++k)
            f[k] = __half22float2(hp[((size_t)idx[k] << 4) + j]);
#pragma unroll
        for (int k = 0; k < 16; ++k) {
            ax = fmaf(msk[k], f[k].x, ax);
            ay = fmaf(msk[k], f[k].y, ay);
        }
    }
    float dv = dinv[wid];
    float2 fs = __half22float2(hp[((size_t)wid << 4) + j]);
    float2 bb = ((const float2*)bias)[j];
    float vx = dv * (ax + fs.x) + bb.x;
    float vy = dv * (ay + fs.y) + bb.y;
    float2 r;
    r.x = vx > 0.f ? vx : expm1f(vx);
    r.y = vy > 0.f ? vy : expm1f(vy);
    ((float2*)(g + ((size_t)wid << 5)))[j] = r;
}

// ---- cooperative head: conv1d(32->16,k=3)+relu+fc(16->22), 64 rows/block ----
__global__ __launch_bounds__(256) void k_head(const float* __restrict__ g2, const float* __restrict__ cw,
                                              const float* __restrict__ cb, const float* __restrict__ fw,
                                              const float* __restrict__ fb, float* __restrict__ out,
                                              int nrows) {
    __shared__ float tile[(HROWS + 2) * 36];
    __shared__ float scwT[96 * 16];
    __shared__ float ytile[HROWS * 20];
    __shared__ float sfwT[22 * 16];
    __shared__ float scb[16], sfb[22];
    int base = blockIdx.x * HROWS;
    int rcnt = nrows - base; if (rcnt > HROWS) rcnt = HROWS;
    for (int i = threadIdx.x; i < 1536; i += 256) {
        int co = i / 96, rem = i - co * 96;
        scwT[rem * 16 + co] = cw[i];
    }
    for (int i = threadIdx.x; i < 352; i += 256) {
        int co = i / 22, col = i - co * 22;
        sfwT[col * 16 + co] = fw[i];
    }
    if (threadIdx.x < 16) scb[threadIdx.x] = cb[threadIdx.x];
    if (threadIdx.x < 22) sfb[threadIdx.x] = fb[threadIdx.x];
    int nload4 = (rcnt + 2) * 8;
    for (int i = threadIdx.x; i < nload4; i += 256) {
        int r = i >> 3, c4 = i & 7;
        float4 v = *(const float4*)(g2 + (size_t)(base + r) * 32 + c4 * 4);
        *(float4*)&tile[r * 36 + c4 * 4] = v;
    }
    __syncthreads();
    int r = threadIdx.x >> 2;
    int c0 = threadIdx.x & 3;
    if (r < rcnt) {
        float4 acc = { scb[c0 * 4], scb[c0 * 4 + 1], scb[c0 * 4 + 2], scb[c0 * 4 + 3] };
#pragma unroll
        for (int k = 0; k < 3; ++k) {
            const float* tr = &tile[(r + k) * 36];
#pragma unroll
            for (int ci4 = 0; ci4 < 8; ++ci4) {
                float4 xv = *(const float4*)&tr[ci4 * 4];
#pragma unroll
                for (int q = 0; q < 4; ++q) {
                    int ci = ci4 * 4 + q;
                    float4 wv = *(const float4*)&scwT[(ci * 3 + k) * 16 + c0 * 4];
                    float xq = q == 0 ? xv.x : q == 1 ? xv.y : q == 2 ? xv.z : xv.w;
                    acc.x += xq * wv.x;
                    acc.y += xq * wv.y;
                    acc.z += xq * wv.z;
                    acc.w += xq * wv.w;
                }
            }
        }
        float4 yv;
        yv.x = acc.x > 0.f ? acc.x : 0.f;
        yv.y = acc.y > 0.f ? acc.y : 0.f;
        yv.z = acc.z > 0.f ? acc.z : 0.f;
        yv.w = acc.w > 0.f ? acc.w : 0.f;
        *(float4*)&ytile[r * 20 + c0 * 4] = yv;
    }
    __syncthreads();
    int items = rcnt * 22;
    for (int it = threadIdx.x; it < items; it += 256) {
        int row = it / 22, col = it - row * 22;
        const float* yr = &ytile[row * 20];
        const float* wc = &sfwT[col * 16];
        float s = sfb[col];
#pragma unroll
        for (int co4 = 0; co4 < 4; ++co4) {
            float4 yv = *(const float4*)&yr[co4 * 4];
            float4 wv = *(const float4*)&wc[co4 * 4];
            s += yv.x * wv.x + yv.y * wv.y + yv.z * wv.z + yv.w * wv.w;
        }
        out[(size_t)base * 22 + it] = s;
    }
}

extern "C" void kernel_launch(void* const* d_in, const int* in_sizes, int n_in,
                              void* d_out, int out_size, void* d_ws, size_t ws_size,
                              hipStream_t stream) {
    const float* x  = (const float*)d_in[0];
    const int*   ei = (const int*)d_in[1];   // int32 (JAX x64 disabled)
    const float* W1 = (const float*)d_in[2];
    const float* b1 = (const float*)d_in[3];
    const float* W2 = (const float*)d_in[4];
    const float* b2 = (const float*)d_in[5];
    const float* cw = (const float*)d_in[6];
    const float* cb = (const float*)d_in[7];
    const float* fw = (const float*)d_in[8];
    const float* fb = (const float*)d_in[9];
    float* out = (float*)d_out;

    int N = in_sizes[0] / 8;       // 100000
    int E = in_sizes[1] / 2;       // 3200000
    const int* src = ei;
    const int* dst = ei + E;
    int NB = (N + BKT_NODES - 1) >> BKT_SHIFT;  // 391

    auto alignB = [](size_t v) { return (v + 1023) & ~(size_t)1023; };
    char* wsb = (char*)d_ws;
    size_t o = 0;
    int* bcnt = (int*)(wsb + o);      o += 2048;
    int* boff = (int*)(wsb + o);      o += 2048;
    int* bcur = (int*)(wsb + o);      o += 2048;
    int* rowstart = (int*)(wsb + o);  o += alignB((size_t)(N + 1) * 4);
    float* dinv = (float*)(wsb + o);  o += alignB((size_t)N * 4);
    int* csr = (int*)(wsb + o);       o += alignB((size_t)E * 4 + 256);
    __half2* hx = (__half2*)(wsb + o);  o += alignB((size_t)N * 8 * 2);   // [N][8] fp16
    __half* hw2 = (__half*)(wsb + o);   o += alignB((size_t)N * 32 * 2);  // [N][32] fp16
    float* B = (float*)(wsb + o);     o += (size_t)N * 64 * 4;            // g2
    int* ebuf = (int*)B;              // dead before B's first write

    hipMemsetAsync(bcnt, 0, (size_t)NB * sizeof(int), stream);
    k_hist<<<(E + 4095) / 4096, 256, 0, stream>>>(dst, bcnt, E, NB);
    k_bscan<<<1, 512, 0, stream>>>(bcnt, boff, bcur, NB, E);
    k_part<<<(E + 8191) / 8192, 1024, 0, stream>>>(src, dst, bcur, ebuf, E, NB);
    k_lsort<<<NB, 256, 0, stream>>>(boff, ebuf, x, rowstart, dinv, hx, csr, N, NB);

    k_agg1g<<<(int)(((size_t)N * 4 + 255) / 256), 256, 0, stream>>>(rowstart, csr, dinv, hx, W1, b1, W2, hw2, N);

    k_aggr32p<<<(int)(((size_t)N * 16 + 255) / 256), 256, 0, stream>>>(rowstart, csr, dinv, hw2, b2, B, N);

    k_head<<<(N - 2 + HROWS - 1) / HROWS, 256, 0, stream>>>(B, cw, cb, fw, fb, out, N - 2);
}

// Round 19
// 181.638 us; speedup vs baseline: 1.3860x; 1.0120x over previous
//
#include <hip/hip_runtime.h>
#include <hip/hip_fp16.h>
#include <math.h>

#define BKT_SHIFT 8
#define BKT_NODES 256
#define HROWS 64

// ---- pass 1: per-bucket histogram (int4-vectorized dst read) ----
__global__ __launch_bounds__(256) void k_hist(const int* __restrict__ dst,
                                              int* __restrict__ bcnt, int E, int NB) {
    __shared__ int lh[512];
    for (int i = threadIdx.x; i < NB; i += 256) lh[i] = 0;
    __syncthreads();
    int base = blockIdx.x * 4096;
    if (base + 4096 <= E) {
        const int4* d4 = (const int4*)(dst + base);
#pragma unroll
        for (int k = 0; k < 4; ++k) {
            int4 v = d4[k * 256 + threadIdx.x];
            atomicAdd(&lh[v.x >> BKT_SHIFT], 1);
            atomicAdd(&lh[v.y >> BKT_SHIFT], 1);
            atomicAdd(&lh[v.z >> BKT_SHIFT], 1);
            atomicAdd(&lh[v.w >> BKT_SHIFT], 1);
        }
    } else {
        for (int k = 0; k < 16; ++k) {
            int i = base + k * 256 + threadIdx.x;
            if (i < E) atomicAdd(&lh[dst[i] >> BKT_SHIFT], 1);
        }
    }
    __syncthreads();
    for (int i = threadIdx.x; i < NB; i += 256)
        if (lh[i]) atomicAdd(&bcnt[i], lh[i]);
}

// ---- exclusive scan over NB buckets (single block) ----
__global__ __launch_bounds__(512) void k_bscan(const int* __restrict__ bc,
                                               int* __restrict__ boff,
                                               int* __restrict__ bcur, int NB, int E) {
    __shared__ int s[512];
    __shared__ int carry;
    if (threadIdx.x == 0) carry = 0;
    __syncthreads();
    for (int base = 0; base < NB; base += 512) {
        int i = base + threadIdx.x;
        int v = (i < NB) ? bc[i] : 0;
        s[threadIdx.x] = v;
        __syncthreads();
        for (int off = 1; off < 512; off <<= 1) {
            int t = (threadIdx.x >= off) ? s[threadIdx.x - off] : 0;
            __syncthreads();
            s[threadIdx.x] += t;
            __syncthreads();
        }
        if (i < NB) {
            int ex = carry + s[threadIdx.x] - v;
            boff[i] = ex;
            bcur[i] = ex;
        }
        __syncthreads();
        if (threadIdx.x == 0) carry += s[511];
        __syncthreads();
    }
    if (threadIdx.x == 0) boff[NB] = E;
}

// ---- pass 2: partition edges; record = (d&255)<<24 | src ----
__global__ __launch_bounds__(1024) void k_part(const int* __restrict__ src,
                                               const int* __restrict__ dst,
                                               int* __restrict__ bcur,
                                               int* __restrict__ ebuf, int E, int NB) {
    __shared__ int lh[512];
    for (int i = threadIdx.x; i < NB; i += 1024) lh[i] = 0;
    __syncthreads();
    int base = blockIdx.x * 8192;
    if (base + 8192 <= E) {
        const int4* d4 = (const int4*)(dst + base);
#pragma unroll
        for (int k = 0; k < 2; ++k) {
            int4 v = d4[k * 1024 + threadIdx.x];
            atomicAdd(&lh[v.x >> BKT_SHIFT], 1);
            atomicAdd(&lh[v.y >> BKT_SHIFT], 1);
            atomicAdd(&lh[v.z >> BKT_SHIFT], 1);
            atomicAdd(&lh[v.w >> BKT_SHIFT], 1);
        }
    } else {
        for (int k = 0; k < 8; ++k) {
            int i = base + k * 1024 + threadIdx.x;
            if (i < E) atomicAdd(&lh[dst[i] >> BKT_SHIFT], 1);
        }
    }
    __syncthreads();
    for (int t = threadIdx.x; t < NB; t += 1024) {
        int c = lh[t];
        lh[t] = c ? atomicAdd(&bcur[t], c) : 0;
    }
    __syncthreads();
    if (base + 8192 <= E) {
        const int4* d4 = (const int4*)(dst + base);
        const int4* s4 = (const int4*)(src + base);
#pragma unroll
        for (int k = 0; k < 2; ++k) {
            int4 dv = d4[k * 1024 + threadIdx.x];
            int4 sv = s4[k * 1024 + threadIdx.x];
            int p;
            p = atomicAdd(&lh[dv.x >> BKT_SHIFT], 1); ebuf[p] = ((dv.x & 255) << 24) | sv.x;
            p = atomicAdd(&lh[dv.y >> BKT_SHIFT], 1); ebuf[p] = ((dv.y & 255) << 24) | sv.y;
            p = atomicAdd(&lh[dv.z >> BKT_SHIFT], 1); ebuf[p] = ((dv.z & 255) << 24) | sv.z;
            p = atomicAdd(&lh[dv.w >> BKT_SHIFT], 1); ebuf[p] = ((dv.w & 255) << 24) | sv.w;
        }
    } else {
        for (int k = 0; k < 8; ++k) {
            int i = base + k * 1024 + threadIdx.x;
            if (i < E) {
                int d = dst[i];
                int p = atomicAdd(&lh[d >> BKT_SHIFT], 1);
                ebuf[p] = ((d & 255) << 24) | src[i];
            }
        }
    }
}

// ---- pass 3: counting sort + dinv + hx (fused) ----
__global__ __launch_bounds__(256) void k_lsort(const int* __restrict__ boff,
                                               const int* __restrict__ ebuf,
                                               const float* __restrict__ x,
                                               int* __restrict__ rowstart,
                                               float* __restrict__ dinv,
                                               __half2* __restrict__ hx,
                                               int* __restrict__ csr, int n, int NB) {
    __shared__ int off[256];
    __shared__ int cnt[256];
    int b = blockIdx.x;
    int start = boff[b], end = boff[b + 1];
    cnt[threadIdx.x] = 0;
    __syncthreads();
    for (int i = start + threadIdx.x; i < end; i += 256)
        atomicAdd(&cnt[((unsigned)ebuf[i]) >> 24], 1);
    __syncthreads();
    int v = cnt[threadIdx.x];
    off[threadIdx.x] = v;
    __syncthreads();
    for (int o = 1; o < 256; o <<= 1) {
        int t = (threadIdx.x >= o) ? off[threadIdx.x - o] : 0;
        __syncthreads();
        off[threadIdx.x] += t;
        __syncthreads();
    }
    int excl = off[threadIdx.x] - v;
    int node = (b << BKT_SHIFT) + threadIdx.x;
    if (node < n) {
        rowstart[node] = start + excl;
        float dv = rsqrtf((float)v + 1.0f);  // +1 = self-loop
        dinv[node] = dv;
        const float4* xp = (const float4*)(x + (size_t)node * 8);
        float4 a = xp[0], c = xp[1];
        __half2* hp = hx + (size_t)node * 4;
        hp[0] = __floats2half2_rn(a.x * dv, a.y * dv);
        hp[1] = __floats2half2_rn(a.z * dv, a.w * dv);
        hp[2] = __floats2half2_rn(c.x * dv, c.y * dv);
        hp[3] = __floats2half2_rn(c.z * dv, c.w * dv);
    }
    __syncthreads();
    off[threadIdx.x] = excl;  // reuse as cursor
    __syncthreads();
    for (int i = start + threadIdx.x; i < end; i += 256) {
        int rec = ebuf[i];
        int d = ((unsigned)rec) >> 24;
        int pos = atomicAdd(&off[d], 1);
        csr[start + pos] = rec & 0xFFFFFF;
    }
    if (b == NB - 1 && threadIdx.x == 0) rowstart[n] = end;
}

// ---- fused layer-1 + gemm2: 16 nodes/wave, 4 lanes/node, 16-deep gather,
//      quad-allgather -> g1 (in regs) -> @W2 (transposed LDS) -> butterfly -> hw2 fp16 ----
__global__ __launch_bounds__(256) void k_agg1g(const int* __restrict__ rs, const int* __restrict__ csr,
                                               const float* __restrict__ dinv, const __half2* __restrict__ hx,
                                               const float* __restrict__ W1, const float* __restrict__ bias,
                                               const float* __restrict__ W2, __half* __restrict__ hw2, int n) {
    __shared__ float w[512];        // W1 [8][64]
    __shared__ float sb[64];
    __shared__ float w2t[32 * 66];  // W2 transposed: [j=32][k=64] stride 66 (8B-aligned, odd/2 bank split)
    for (int i = threadIdx.x; i < 512; i += 256) w[i] = W1[i];
    if (threadIdx.x < 64) sb[threadIdx.x] = bias[threadIdx.x];
    for (int i = threadIdx.x; i < 2048; i += 256) {
        int r = i >> 5, c = i & 31;
        w2t[c * 66 + r] = W2[i];
    }
    __syncthreads();
    int wid = (blockIdx.x * 256 + threadIdx.x) >> 2;   // node
    if (wid >= n) return;
    int jp = threadIdx.x & 3;          // half2 index (feats 2jp, 2jp+1)
    int start = rs[wid], end = rs[wid + 1];
    float ax = 0.f, ay = 0.f;
    for (int i = start; i < end; i += 16) {
        int idx[16];
        float msk[16];
#pragma unroll
        for (int k = 0; k < 16; ++k) {
            int ii = i + k;
            bool ok = ii < end;
            idx[k] = ok ? csr[ii] : wid;
            msk[k] = ok ? 1.f : 0.f;
        }
        float2 f[16];
#pragma unroll
        for (int k = 0; k < 16; ++k)
            f[k] = __half22float2(hx[((size_t)idx[k] << 2) + jp]);
#pragma unroll
        for (int k = 0; k < 16; ++k) {
            ax = fmaf(msk[k], f[k].x, ax);
            ay = fmaf(msk[k], f[k].y, ay);
        }
    }
    {   // self-loop row
        float2 f = __half22float2(hx[((size_t)wid << 2) + jp]);
        ax += f.x; ay += f.y;
    }
    // quad allgather of aggregated input feats
    float bx = __shfl_xor(ax, 1), by = __shfl_xor(ay, 1);
    float cx = __shfl_xor(ax, 2), cy = __shfl_xor(ay, 2);
    float dx = __shfl_xor(bx, 2), dy = __shfl_xor(by, 2);
    float dv = dinv[wid];
    int fb = jp * 16;   // this lane's g1 slice [fb, fb+16)
    const float* r0 = &w[(2 * jp) * 64 + fb];          const float* r1 = r0 + 64;
    const float* r2 = &w[(2 * (jp ^ 1)) * 64 + fb];    const float* r3 = r2 + 64;
    const float* r4 = &w[(2 * (jp ^ 2)) * 64 + fb];    const float* r5 = r4 + 64;
    const float* r6 = &w[(2 * (jp ^ 3)) * 64 + fb];    const float* r7 = r6 + 64;
    const float* sbp = &sb[fb];
    float gv[16];
#pragma unroll
    for (int m4 = 0; m4 < 4; ++m4) {
        float4 wa = *(const float4*)&r0[m4 * 4];
        float4 wb = *(const float4*)&r1[m4 * 4];
        float4 wc = *(const float4*)&r2[m4 * 4];
        float4 wd = *(const float4*)&r3[m4 * 4];
        float4 we = *(const float4*)&r4[m4 * 4];
        float4 wf = *(const float4*)&r5[m4 * 4];
        float4 wg = *(const float4*)&r6[m4 * 4];
        float4 wh = *(const float4*)&r7[m4 * 4];
        float4 o;
        o.x = dv * (ax * wa.x + ay * wb.x + bx * wc.x + by * wd.x + cx * we.x + cy * wf.x + dx * wg.x + dy * wh.x) + sbp[m4 * 4 + 0];
        o.y = dv * (ax * wa.y + ay * wb.y + bx * wc.y + by * wd.y + cx * we.y + cy * wf.y + dx * wg.y + dy * wh.y) + sbp[m4 * 4 + 1];
        o.z = dv * (ax * wa.z + ay * wb.z + bx * wc.z + by * wd.z + cx * we.z + cy * wf.z + dx * wg.z + dy * wh.z) + sbp[m4 * 4 + 2];
        o.w = dv * (ax * wa.w + ay * wb.w + bx * wc.w + by * wd.w + cx * we.w + cy * wf.w + dx * wg.w + dy * wh.w) + sbp[m4 * 4 + 3];
        o.x = o.x > 0.f ? o.x : expm1f(o.x);
        o.y = o.y > 0.f ? o.y : expm1f(o.y);
        o.z = o.z > 0.f ? o.z : expm1f(o.z);
        o.w = o.w > 0.f ? o.w : expm1f(o.w);
        gv[m4 * 4 + 0] = o.x;
        gv[m4 * 4 + 1] = o.y;
        gv[m4 * 4 + 2] = o.z;
        gv[m4 * 4 + 3] = o.w;
    }
    // second GEMM via transposed W2: partial[j] over this lane's 16 g1 values
    float4 acc[8];
#pragma unroll
    for (int j4 = 0; j4 < 8; ++j4) {
        float4 a;
#pragma unroll
        for (int jc = 0; jc < 4; ++jc) {
            const float2* wr = (const float2*)&w2t[(j4 * 4 + jc) * 66 + fb];
            float s = 0.f;
#pragma unroll
            for (int t = 0; t < 8; ++t) {
                float2 wv = wr[t];
                s = fmaf(wv.x, gv[2 * t], s);
                s = fmaf(wv.y, gv[2 * t + 1], s);
            }
            if (jc == 0) a.x = s;
            else if (jc == 1) a.y = s;
            else if (jc == 2) a.z = s;
            else a.w = s;
        }
        acc[j4] = a;
    }
    // butterfly reduce-scatter across the 4 lanes (static indexing only)
    bool hi1 = (jp & 1) != 0;
    float4 keep1[4];
#pragma unroll
    for (int i = 0; i < 4; ++i) {
        float4 lo = acc[i], hi = acc[i + 4];
        float4 mine, send;
        mine.x = hi1 ? hi.x : lo.x;  send.x = hi1 ? lo.x : hi.x;
        mine.y = hi1 ? hi.y : lo.y;  send.y = hi1 ? lo.y : hi.y;
        mine.z = hi1 ? hi.z : lo.z;  send.z = hi1 ? lo.z : hi.z;
        mine.w = hi1 ? hi.w : lo.w;  send.w = hi1 ? lo.w : hi.w;
        mine.x += __shfl_xor(send.x, 1);
        mine.y += __shfl_xor(send.y, 1);
        mine.z += __shfl_xor(send.z, 1);
        mine.w += __shfl_xor(send.w, 1);
        keep1[i] = mine;
    }
    bool hi2 = (jp & 2) != 0;
    float4 fin[2];
#pragma unroll
    for (int i = 0; i < 2; ++i) {
        float4 lo = keep1[i], hi = keep1[i + 2];
        float4 mine, send;
        mine.x = hi2 ? hi.x : lo.x;  send.x = hi2 ? lo.x : hi.x;
        mine.y = hi2 ? hi.y : lo.y;  send.y = hi2 ? lo.y : hi.y;
        mine.z = hi2 ? hi.z : lo.z;  send.z = hi2 ? lo.z : hi.z;
        mine.w = hi2 ? hi.w : lo.w;  send.w = hi2 ? lo.w : hi.w;
        mine.x += __shfl_xor(send.x, 2);
        mine.y += __shfl_xor(send.y, 2);
        mine.z += __shfl_xor(send.z, 2);
        mine.w += __shfl_xor(send.w, 2);
        fin[i] = mine;
    }
    // lane jp holds finished j in [jb, jb+8), jb = (jp&1)*16 + (jp&2)*4
    int jb = (jp & 1) * 16 + (jp & 2) * 4;
    __half2 h01 = __floats2half2_rn(fin[0].x * dv, fin[0].y * dv);
    __half2 h23 = __floats2half2_rn(fin[0].z * dv, fin[0].w * dv);
    __half2 h45 = __floats2half2_rn(fin[1].x * dv, fin[1].y * dv);
    __half2 h67 = __floats2half2_rn(fin[1].z * dv, fin[1].w * dv);
    uint4 u;
    u.x = *(unsigned*)&h01; u.y = *(unsigned*)&h23;
    u.z = *(unsigned*)&h45; u.w = *(unsigned*)&h67;
    *(uint4*)((char*)hw2 + (size_t)wid * 64 + jb * 2) = u;
}

// ---- layer-2: 4 nodes/wave, 16 lanes/node, 16-deep predicated gather ----
__global__ __launch_bounds__(256) void k_aggr32p(const int* __restrict__ rs, const int* __restrict__ csr,
                                                 const float* __restrict__ dinv, const __half* __restrict__ hw,
                                                 const float* __restrict__ bias, float* __restrict__ g, int n) {
    int wid = (blockIdx.x * 256 + threadIdx.x) >> 4;
    if (wid >= n) return;
    int j = threadIdx.x & 15;           // feature pair (feats 2j, 2j+1)
    int start = rs[wid], end = rs[wid + 1];
    const __half2* hp = (const __half2*)hw;
    float ax = 0.f, ay = 0.f;
    for (int i = start; i < end; i += 16) {
        int idx[16];
        float msk[16];
#pragma unroll
        for (int k = 0; k < 16; ++k) {
            int ii = i + k;
            bool ok = ii < end;
            idx[k] = ok ? csr[ii] : wid;
            msk[k] = ok ? 1.f : 0.f;
        }
        float2 f[16];
#pragma unroll
        for (int k = 0; k < 16; ++k)
            f[k] = __half22float2(hp[((size_t)idx[k] << 4) + j]);
#pragma unroll
        for (int k = 0; k < 16; ++k) {
            ax = fmaf(msk[k], f[k].x, ax);
            ay = fmaf(msk[k], f[k].y, ay);
        }
    }
    float dv = dinv[wid];
    float2 fs = __half22float2(hp[((size_t)wid << 4) + j]);
    float2 bb = ((const float2*)bias)[j];
    float vx = dv * (ax + fs.x) + bb.x;
    float vy = dv * (ay + fs.y) + bb.y;
    float2 r;
    r.x = vx > 0.f ? vx : expm1f(vx);
    r.y = vy > 0.f ? vy : expm1f(vy);
    ((float2*)(g + ((size_t)wid << 5)))[j] = r;
}

// ---- cooperative head: conv1d(32->16,k=3)+relu+fc(16->22), 64 rows/block ----
__global__ __launch_bounds__(256) void k_head(const float* __restrict__ g2, const float* __restrict__ cw,
                                              const float* __restrict__ cb, const float* __restrict__ fw,
                                              const float* __restrict__ fb, float* __restrict__ out,
                                              int nrows) {
    __shared__ float tile[(HROWS + 2) * 36];
    __shared__ float scwT[96 * 16];
    __shared__ float ytile[HROWS * 20];
    __shared__ float sfwT[22 * 16];
    __shared__ float scb[16], sfb[22];
    int base = blockIdx.x * HROWS;
    int rcnt = nrows - base; if (rcnt > HROWS) rcnt = HROWS;
    for (int i = threadIdx.x; i < 1536; i += 256) {
        int co = i / 96, rem = i - co * 96;
        scwT[rem * 16 + co] = cw[i];
    }
    for (int i = threadIdx.x; i < 352; i += 256) {
        int co = i / 22, col = i - co * 22;
        sfwT[col * 16 + co] = fw[i];
    }
    if (threadIdx.x < 16) scb[threadIdx.x] = cb[threadIdx.x];
    if (threadIdx.x < 22) sfb[threadIdx.x] = fb[threadIdx.x];
    int nload4 = (rcnt + 2) * 8;
    for (int i = threadIdx.x; i < nload4; i += 256) {
        int r = i >> 3, c4 = i & 7;
        float4 v = *(const float4*)(g2 + (size_t)(base + r) * 32 + c4 * 4);
        *(float4*)&tile[r * 36 + c4 * 4] = v;
    }
    __syncthreads();
    int r = threadIdx.x >> 2;
    int c0 = threadIdx.x & 3;
    if (r < rcnt) {
        float4 acc = { scb[c0 * 4], scb[c0 * 4 + 1], scb[c0 * 4 + 2], scb[c0 * 4 + 3] };
#pragma unroll
        for (int k = 0; k < 3; ++k) {
            const float* tr = &tile[(r + k) * 36];
#pragma unroll
            for (int ci4 = 0; ci4 < 8; ++ci4) {
                float4 xv = *(const float4*)&tr[ci4 * 4];
#pragma unroll
                for (int q = 0; q < 4; ++q) {
                    int ci = ci4 * 4 + q;
                    float4 wv = *(const float4*)&scwT[(ci * 3 + k) * 16 + c0 * 4];
                    float xq = q == 0 ? xv.x : q == 1 ? xv.y : q == 2 ? xv.z : xv.w;
                    acc.x += xq * wv.x;
                    acc.y += xq * wv.y;
                    acc.z += xq * wv.z;
                    acc.w += xq * wv.w;
                }
            }
        }
        float4 yv;
        yv.x = acc.x > 0.f ? acc.x : 0.f;
        yv.y = acc.y > 0.f ? acc.y : 0.f;
        yv.z = acc.z > 0.f ? acc.z : 0.f;
        yv.w = acc.w > 0.f ? acc.w : 0.f;
        *(float4*)&ytile[r * 20 + c0 * 4] = yv;
    }
    __syncthreads();
    int items = rcnt * 22;
    for (int it = threadIdx.x; it < items; it += 256) {
        int row = it / 22, col = it - row * 22;
        const float* yr = &ytile[row * 20];
        const float* wc = &sfwT[col * 16];
        float s = sfb[col];
#pragma unroll
        for (int co4 = 0; co4 < 4; ++co4) {
            float4 yv = *(const float4*)&yr[co4 * 4];
            float4 wv = *(const float4*)&wc[co4 * 4];
            s += yv.x * wv.x + yv.y * wv.y + yv.z * wv.z + yv.w * wv.w;
        }
        out[(size_t)base * 22 + it] = s;
    }
}

extern "C" void kernel_launch(void* const* d_in, const int* in_sizes, int n_in,
                              void* d_out, int out_size, void* d_ws, size_t ws_size,
                              hipStream_t stream) {
    const float* x  = (const float*)d_in[0];
    const int*   ei = (const int*)d_in[1];   // int32 (JAX x64 disabled)
    const float* W1 = (const float*)d_in[2];
    const float* b1 = (const float*)d_in[3];
    const float* W2 = (const float*)d_in[4];
    const float* b2 = (const float*)d_in[5];
    const float* cw = (const float*)d_in[6];
    const float* cb = (const float*)d_in[7];
    const float* fw = (const float*)d_in[8];
    const float* fb = (const float*)d_in[9];
    float* out = (float*)d_out;

    int N = in_sizes[0] / 8;       // 100000
    int E = in_sizes[1] / 2;       // 3200000
    const int* src = ei;
    const int* dst = ei + E;
    int NB = (N + BKT_NODES - 1) >> BKT_SHIFT;  // 391

    auto alignB = [](size_t v) { return (v + 1023) & ~(size_t)1023; };
    char* wsb = (char*)d_ws;
    size_t o = 0;
    int* bcnt = (int*)(wsb + o);      o += 2048;
    int* boff = (int*)(wsb + o);      o += 2048;
    int* bcur = (int*)(wsb + o);      o += 2048;
    int* rowstart = (int*)(wsb + o);  o += alignB((size_t)(N + 1) * 4);
    float* dinv = (float*)(wsb + o);  o += alignB((size_t)N * 4);
    int* csr = (int*)(wsb + o);       o += alignB((size_t)E * 4 + 256);
    __half2* hx = (__half2*)(wsb + o);  o += alignB((size_t)N * 8 * 2);   // [N][8] fp16
    __half* hw2 = (__half*)(wsb + o);   o += alignB((size_t)N * 32 * 2);  // [N][32] fp16
    float* B = (float*)(wsb + o);     o += (size_t)N * 64 * 4;            // g2
    int* ebuf = (int*)B;              // dead before B's first write

    hipMemsetAsync(bcnt, 0, (size_t)NB * sizeof(int), stream);
    k_hist<<<(E + 4095) / 4096, 256, 0, stream>>>(dst, bcnt, E, NB);
    k_bscan<<<1, 512, 0, stream>>>(bcnt, boff, bcur, NB, E);
    k_part<<<(E + 8191) / 8192, 1024, 0, stream>>>(src, dst, bcur, ebuf, E, NB);
    k_lsort<<<NB, 256, 0, stream>>>(boff, ebuf, x, rowstart, dinv, hx, csr, N, NB);

    k_agg1g<<<(int)(((size_t)N * 4 + 255) / 256), 256, 0, stream>>>(rowstart, csr, dinv, hx, W1, b1, W2, hw2, N);

    k_aggr32p<<<(int)(((size_t)N * 16 + 255) / 256), 256, 0, stream>>>(rowstart, csr, dinv, hw2, b2, B, N);

    k_head<<<(N - 2 + HROWS - 1) / HROWS, 256, 0, stream>>>(B, cw, cb, fw, fb, out, N - 2);
}

// Round 20
// 172.044 us; speedup vs baseline: 1.4633x; 1.0558x over previous
//
#include <hip/hip_runtime.h>
#include <hip/hip_fp16.h>
#include <math.h>

#define BKT_SHIFT 8
#define BKT_NODES 256
#define HROWS 64

// ---- pass 1: per-bucket histogram (int4-vectorized dst read) ----
__global__ __launch_bounds__(256) void k_hist(const int* __restrict__ dst,
                                              int* __restrict__ bcnt, int E, int NB) {
    __shared__ int lh[512];
    for (int i = threadIdx.x; i < NB; i += 256) lh[i] = 0;
    __syncthreads();
    int base = blockIdx.x * 4096;
    if (base + 4096 <= E) {
        const int4* d4 = (const int4*)(dst + base);
#pragma unroll
        for (int k = 0; k < 4; ++k) {
            int4 v = d4[k * 256 + threadIdx.x];
            atomicAdd(&lh[v.x >> BKT_SHIFT], 1);
            atomicAdd(&lh[v.y >> BKT_SHIFT], 1);
            atomicAdd(&lh[v.z >> BKT_SHIFT], 1);
            atomicAdd(&lh[v.w >> BKT_SHIFT], 1);
        }
    } else {
        for (int k = 0; k < 16; ++k) {
            int i = base + k * 256 + threadIdx.x;
            if (i < E) atomicAdd(&lh[dst[i] >> BKT_SHIFT], 1);
        }
    }
    __syncthreads();
    for (int i = threadIdx.x; i < NB; i += 256)
        if (lh[i]) atomicAdd(&bcnt[i], lh[i]);
}

// ---- exclusive scan over NB buckets (single block) ----
__global__ __launch_bounds__(512) void k_bscan(const int* __restrict__ bc,
                                               int* __restrict__ boff,
                                               int* __restrict__ bcur, int NB, int E) {
    __shared__ int s[512];
    __shared__ int carry;
    if (threadIdx.x == 0) carry = 0;
    __syncthreads();
    for (int base = 0; base < NB; base += 512) {
        int i = base + threadIdx.x;
        int v = (i < NB) ? bc[i] : 0;
        s[threadIdx.x] = v;
        __syncthreads();
        for (int off = 1; off < 512; off <<= 1) {
            int t = (threadIdx.x >= off) ? s[threadIdx.x - off] : 0;
            __syncthreads();
            s[threadIdx.x] += t;
            __syncthreads();
        }
        if (i < NB) {
            int ex = carry + s[threadIdx.x] - v;
            boff[i] = ex;
            bcur[i] = ex;
        }
        __syncthreads();
        if (threadIdx.x == 0) carry += s[511];
        __syncthreads();
    }
    if (threadIdx.x == 0) boff[NB] = E;
}

// ---- pass 2: partition edges; record = (d&255)<<24 | src ----
__global__ __launch_bounds__(1024) void k_part(const int* __restrict__ src,
                                               const int* __restrict__ dst,
                                               int* __restrict__ bcur,
                                               int* __restrict__ ebuf, int E, int NB) {
    __shared__ int lh[512];
    for (int i = threadIdx.x; i < NB; i += 1024) lh[i] = 0;
    __syncthreads();
    int base = blockIdx.x * 8192;
    if (base + 8192 <= E) {
        const int4* d4 = (const int4*)(dst + base);
#pragma unroll
        for (int k = 0; k < 2; ++k) {
            int4 v = d4[k * 1024 + threadIdx.x];
            atomicAdd(&lh[v.x >> BKT_SHIFT], 1);
            atomicAdd(&lh[v.y >> BKT_SHIFT], 1);
            atomicAdd(&lh[v.z >> BKT_SHIFT], 1);
            atomicAdd(&lh[v.w >> BKT_SHIFT], 1);
        }
    } else {
        for (int k = 0; k < 8; ++k) {
            int i = base + k * 1024 + threadIdx.x;
            if (i < E) atomicAdd(&lh[dst[i] >> BKT_SHIFT], 1);
        }
    }
    __syncthreads();
    for (int t = threadIdx.x; t < NB; t += 1024) {
        int c = lh[t];
        lh[t] = c ? atomicAdd(&bcur[t], c) : 0;
    }
    __syncthreads();
    if (base + 8192 <= E) {
        const int4* d4 = (const int4*)(dst + base);
        const int4* s4 = (const int4*)(src + base);
#pragma unroll
        for (int k = 0; k < 2; ++k) {
            int4 dv = d4[k * 1024 + threadIdx.x];
            int4 sv = s4[k * 1024 + threadIdx.x];
            int p;
            p = atomicAdd(&lh[dv.x >> BKT_SHIFT], 1); ebuf[p] = ((dv.x & 255) << 24) | sv.x;
            p = atomicAdd(&lh[dv.y >> BKT_SHIFT], 1); ebuf[p] = ((dv.y & 255) << 24) | sv.y;
            p = atomicAdd(&lh[dv.z >> BKT_SHIFT], 1); ebuf[p] = ((dv.z & 255) << 24) | sv.z;
            p = atomicAdd(&lh[dv.w >> BKT_SHIFT], 1); ebuf[p] = ((dv.w & 255) << 24) | sv.w;
        }
    } else {
        for (int k = 0; k < 8; ++k) {
            int i = base + k * 1024 + threadIdx.x;
            if (i < E) {
                int d = dst[i];
                int p = atomicAdd(&lh[d >> BKT_SHIFT], 1);
                ebuf[p] = ((d & 255) << 24) | src[i];
            }
        }
    }
}

// ---- pass 3: counting sort + dinv + hx (fused) ----
__global__ __launch_bounds__(256) void k_lsort(const int* __restrict__ boff,
                                               const int* __restrict__ ebuf,
                                               const float* __restrict__ x,
                                               int* __restrict__ rowstart,
                                               float* __restrict__ dinv,
                                               __half2* __restrict__ hx,
                                               int* __restrict__ csr, int n, int NB) {
    __shared__ int off[256];
    __shared__ int cnt[256];
    int b = blockIdx.x;
    int start = boff[b], end = boff[b + 1];
    cnt[threadIdx.x] = 0;
    __syncthreads();
    for (int i = start + threadIdx.x; i < end; i += 256)
        atomicAdd(&cnt[((unsigned)ebuf[i]) >> 24], 1);
    __syncthreads();
    int v = cnt[threadIdx.x];
    off[threadIdx.x] = v;
    __syncthreads();
    for (int o = 1; o < 256; o <<= 1) {
        int t = (threadIdx.x >= o) ? off[threadIdx.x - o] : 0;
        __syncthreads();
        off[threadIdx.x] += t;
        __syncthreads();
    }
    int excl = off[threadIdx.x] - v;
    int node = (b << BKT_SHIFT) + threadIdx.x;
    if (node < n) {
        rowstart[node] = start + excl;
        float dv = rsqrtf((float)v + 1.0f);  // +1 = self-loop
        dinv[node] = dv;
        const float4* xp = (const float4*)(x + (size_t)node * 8);
        float4 a = xp[0], c = xp[1];
        __half2* hp = hx + (size_t)node * 4;
        hp[0] = __floats2half2_rn(a.x * dv, a.y * dv);
        hp[1] = __floats2half2_rn(a.z * dv, a.w * dv);
        hp[2] = __floats2half2_rn(c.x * dv, c.y * dv);
        hp[3] = __floats2half2_rn(c.z * dv, c.w * dv);
    }
    __syncthreads();
    off[threadIdx.x] = excl;  // reuse as cursor
    __syncthreads();
    for (int i = start + threadIdx.x; i < end; i += 256) {
        int rec = ebuf[i];
        int d = ((unsigned)rec) >> 24;
        int pos = atomicAdd(&off[d], 1);
        csr[start + pos] = rec & 0xFFFFFF;
    }
    if (b == NB - 1 && threadIdx.x == 0) rowstart[n] = end;
}

// ---- fused layer-1 + gemm2: 16 nodes/wave, 4 lanes/node, 16-deep gather,
//      quad-allgather -> g1 (in regs) -> @W2 (k-rotated, conflict-free) -> butterfly -> hw2 ----
__global__ __launch_bounds__(256) void k_agg1g(const int* __restrict__ rs, const int* __restrict__ csr,
                                               const float* __restrict__ dinv, const __half2* __restrict__ hx,
                                               const float* __restrict__ W1, const float* __restrict__ bias,
                                               const float* __restrict__ W2, __half* __restrict__ hw2, int n) {
    __shared__ float w[512];        // W1 [8][64]
    __shared__ float sb[64];
    __shared__ float w2s[64 * 36];  // W2 [64][32] padded to stride 36 (16B-aligned rows)
    for (int i = threadIdx.x; i < 512; i += 256) w[i] = W1[i];
    if (threadIdx.x < 64) sb[threadIdx.x] = bias[threadIdx.x];
    for (int i = threadIdx.x; i < 2048; i += 256) {
        int r = i >> 5, c = i & 31;
        w2s[r * 36 + c] = W2[i];
    }
    __syncthreads();
    int wid = (blockIdx.x * 256 + threadIdx.x) >> 2;   // node
    if (wid >= n) return;
    int jp = threadIdx.x & 3;          // half2 index (feats 2jp, 2jp+1)
    int start = rs[wid], end = rs[wid + 1];
    float ax = 0.f, ay = 0.f;
    for (int i = start; i < end; i += 16) {
        int idx[16];
        float msk[16];
#pragma unroll
        for (int k = 0; k < 16; ++k) {
            int ii = i + k;
            bool ok = ii < end;
            idx[k] = ok ? csr[ii] : wid;
            msk[k] = ok ? 1.f : 0.f;
        }
        float2 f[16];
#pragma unroll
        for (int k = 0; k < 16; ++k)
            f[k] = __half22float2(hx[((size_t)idx[k] << 2) + jp]);
#pragma unroll
        for (int k = 0; k < 16; ++k) {
            ax = fmaf(msk[k], f[k].x, ax);
            ay = fmaf(msk[k], f[k].y, ay);
        }
    }
    {   // self-loop row
        float2 f = __half22float2(hx[((size_t)wid << 2) + jp]);
        ax += f.x; ay += f.y;
    }
    // quad allgather of aggregated input feats
    float bx = __shfl_xor(ax, 1), by = __shfl_xor(ay, 1);
    float cx = __shfl_xor(ax, 2), cy = __shfl_xor(ay, 2);
    float dx = __shfl_xor(bx, 2), dy = __shfl_xor(by, 2);
    float dv = dinv[wid];
    int fb = jp * 16;   // this lane's g1 slice [fb, fb+16)
    const float* r0 = &w[(2 * jp) * 64 + fb];          const float* r1 = r0 + 64;
    const float* r2 = &w[(2 * (jp ^ 1)) * 64 + fb];    const float* r3 = r2 + 64;
    const float* r4 = &w[(2 * (jp ^ 2)) * 64 + fb];    const float* r5 = r4 + 64;
    const float* r6 = &w[(2 * (jp ^ 3)) * 64 + fb];    const float* r7 = r6 + 64;
    const float* sbp = &sb[fb];
    float4 o4[4];
#pragma unroll
    for (int m4 = 0; m4 < 4; ++m4) {
        float4 wa = *(const float4*)&r0[m4 * 4];
        float4 wb = *(const float4*)&r1[m4 * 4];
        float4 wc = *(const float4*)&r2[m4 * 4];
        float4 wd = *(const float4*)&r3[m4 * 4];
        float4 we = *(const float4*)&r4[m4 * 4];
        float4 wf = *(const float4*)&r5[m4 * 4];
        float4 wg = *(const float4*)&r6[m4 * 4];
        float4 wh = *(const float4*)&r7[m4 * 4];
        float4 o;
        o.x = dv * (ax * wa.x + ay * wb.x + bx * wc.x + by * wd.x + cx * we.x + cy * wf.x + dx * wg.x + dy * wh.x) + sbp[m4 * 4 + 0];
        o.y = dv * (ax * wa.y + ay * wb.y + bx * wc.y + by * wd.y + cx * we.y + cy * wf.y + dx * wg.y + dy * wh.y) + sbp[m4 * 4 + 1];
        o.z = dv * (ax * wa.z + ay * wb.z + bx * wc.z + by * wd.z + cx * we.z + cy * wf.z + dx * wg.z + dy * wh.z) + sbp[m4 * 4 + 2];
        o.w = dv * (ax * wa.w + ay * wb.w + bx * wc.w + by * wd.w + cx * we.w + cy * wf.w + dx * wg.w + dy * wh.w) + sbp[m4 * 4 + 3];
        o.x = o.x > 0.f ? o.x : expm1f(o.x);
        o.y = o.y > 0.f ? o.y : expm1f(o.y);
        o.z = o.z > 0.f ? o.z : expm1f(o.z);
        o.w = o.w > 0.f ? o.w : expm1f(o.w);
        o4[m4] = o;
    }
    // second GEMM: k-rotated per lane (mm = (m4+jp)&3) -> 2-way LDS conflict only
    float4 acc[8];
#pragma unroll
    for (int j4 = 0; j4 < 8; ++j4) acc[j4] = make_float4(0.f, 0.f, 0.f, 0.f);
#pragma unroll
    for (int m4 = 0; m4 < 4; ++m4) {
        int mm = (m4 + jp) & 3;
        float4 ov;
        {   // static select of o4[mm] (mm is uniform per lane across unroll, but select keeps it register-resident)
            float4 t0 = (mm & 2) ? o4[2] : o4[0];
            float4 t1 = (mm & 2) ? o4[3] : o4[1];
            ov = (mm & 1) ? t1 : t0;
        }
#pragma unroll
        for (int q = 0; q < 4; ++q) {
            float om = q == 0 ? ov.x : q == 1 ? ov.y : q == 2 ? ov.z : ov.w;
            const float4* wr = (const float4*)&w2s[(fb + mm * 4 + q) * 36];
#pragma unroll
            for (int j4 = 0; j4 < 8; ++j4) {
                float4 wv = wr[j4];
                acc[j4].x = fmaf(om, wv.x, acc[j4].x);
                acc[j4].y = fmaf(om, wv.y, acc[j4].y);
                acc[j4].z = fmaf(om, wv.z, acc[j4].z);
                acc[j4].w = fmaf(om, wv.w, acc[j4].w);
            }
        }
    }
    // butterfly reduce-scatter across the 4 lanes (static indexing only)
    bool hi1 = (jp & 1) != 0;
    float4 keep1[4];
#pragma unroll
    for (int i = 0; i < 4; ++i) {
        float4 lo = acc[i], hi = acc[i + 4];
        float4 mine, send;
        mine.x = hi1 ? hi.x : lo.x;  send.x = hi1 ? lo.x : hi.x;
        mine.y = hi1 ? hi.y : lo.y;  send.y = hi1 ? lo.y : hi.y;
        mine.z = hi1 ? hi.z : lo.z;  send.z = hi1 ? lo.z : hi.z;
        mine.w = hi1 ? hi.w : lo.w;  send.w = hi1 ? lo.w : hi.w;
        mine.x += __shfl_xor(send.x, 1);
        mine.y += __shfl_xor(send.y, 1);
        mine.z += __shfl_xor(send.z, 1);
        mine.w += __shfl_xor(send.w, 1);
        keep1[i] = mine;
    }
    bool hi2 = (jp & 2) != 0;
    float4 fin[2];
#pragma unroll
    for (int i = 0; i < 2; ++i) {
        float4 lo = keep1[i], hi = keep1[i + 2];
        float4 mine, send;
        mine.x = hi2 ? hi.x : lo.x;  send.x = hi2 ? lo.x : hi.x;
        mine.y = hi2 ? hi.y : lo.y;  send.y = hi2 ? lo.y : hi.y;
        mine.z = hi2 ? hi.z : lo.z;  send.z = hi2 ? lo.z : hi.z;
        mine.w = hi2 ? hi.w : lo.w;  send.w = hi2 ? lo.w : hi.w;
        mine.x += __shfl_xor(send.x, 2);
        mine.y += __shfl_xor(send.y, 2);
        mine.z += __shfl_xor(send.z, 2);
        mine.w += __shfl_xor(send.w, 2);
        fin[i] = mine;
    }
    // lane jp holds finished j in [jb, jb+8), jb = (jp&1)*16 + (jp&2)*4
    int jb = (jp & 1) * 16 + (jp & 2) * 4;
    __half2 h01 = __floats2half2_rn(fin[0].x * dv, fin[0].y * dv);
    __half2 h23 = __floats2half2_rn(fin[0].z * dv, fin[0].w * dv);
    __half2 h45 = __floats2half2_rn(fin[1].x * dv, fin[1].y * dv);
    __half2 h67 = __floats2half2_rn(fin[1].z * dv, fin[1].w * dv);
    uint4 u;
    u.x = *(unsigned*)&h01; u.y = *(unsigned*)&h23;
    u.z = *(unsigned*)&h45; u.w = *(unsigned*)&h67;
    *(uint4*)((char*)hw2 + (size_t)wid * 64 + jb * 2) = u;
}

// ---- layer-2: 4 nodes/wave, 16 lanes/node, 16-deep predicated gather ----
__global__ __launch_bounds__(256) void k_aggr32p(const int* __restrict__ rs, const int* __restrict__ csr,
                                                 const float* __restrict__ dinv, const __half* __restrict__ hw,
                                                 const float* __restrict__ bias, float* __restrict__ g, int n) {
    int wid = (blockIdx.x * 256 + threadIdx.x) >> 4;
    if (wid >= n) return;
    int j = threadIdx.x & 15;           // feature pair (feats 2j, 2j+1)
    int start = rs[wid], end = rs[wid + 1];
    const __half2* hp = (const __half2*)hw;
    float ax = 0.f, ay = 0.f;
    for (int i = start; i < end; i += 16) {
        int idx[16];
        float msk[16];
#pragma unroll
        for (int k = 0; k < 16; ++k) {
            int ii = i + k;
            bool ok = ii < end;
            idx[k] = ok ? csr[ii] : wid;
            msk[k] = ok ? 1.f : 0.f;
        }
        float2 f[16];
#pragma unroll
        for (int k = 0; k < 16; ++k)
            f[k] = __half22float2(hp[((size_t)idx[k] << 4) + j]);
#pragma unroll
        for (int k = 0; k < 16; ++k) {
            ax = fmaf(msk[k], f[k].x, ax);
            ay = fmaf(msk[k], f[k].y, ay);
        }
    }
    float dv = dinv[wid];
    float2 fs = __half22float2(hp[((size_t)wid << 4) + j]);
    float2 bb = ((const float2*)bias)[j];
    float vx = dv * (ax + fs.x) + bb.x;
    float vy = dv * (ay + fs.y) + bb.y;
    float2 r;
    r.x = vx > 0.f ? vx : expm1f(vx);
    r.y = vy > 0.f ? vy : expm1f(vy);
    ((float2*)(g + ((size_t)wid << 5)))[j] = r;
}

// ---- cooperative head: conv1d(32->16,k=3)+relu+fc(16->22), 64 rows/block ----
__global__ __launch_bounds__(256) void k_head(const float* __restrict__ g2, const float* __restrict__ cw,
                                              const float* __restrict__ cb, const float* __restrict__ fw,
                                              const float* __restrict__ fb, float* __restrict__ out,
                                              int nrows) {
    __shared__ float tile[(HROWS + 2) * 36];
    __shared__ float scwT[96 * 16];
    __shared__ float ytile[HROWS * 20];
    __shared__ float sfwT[22 * 16];
    __shared__ float scb[16], sfb[22];
    int base = blockIdx.x * HROWS;
    int rcnt = nrows - base; if (rcnt > HROWS) rcnt = HROWS;
    for (int i = threadIdx.x; i < 1536; i += 256) {
        int co = i / 96, rem = i - co * 96;
        scwT[rem * 16 + co] = cw[i];
    }
    for (int i = threadIdx.x; i < 352; i += 256) {
        int co = i / 22, col = i - co * 22;
        sfwT[col * 16 + co] = fw[i];
    }
    if (threadIdx.x < 16) scb[threadIdx.x] = cb[threadIdx.x];
    if (threadIdx.x < 22) sfb[threadIdx.x] = fb[threadIdx.x];
    int nload4 = (rcnt + 2) * 8;
    for (int i = threadIdx.x; i < nload4; i += 256) {
        int r = i >> 3, c4 = i & 7;
        float4 v = *(const float4*)(g2 + (size_t)(base + r) * 32 + c4 * 4);
        *(float4*)&tile[r * 36 + c4 * 4] = v;
    }
    __syncthreads();
    int r = threadIdx.x >> 2;
    int c0 = threadIdx.x & 3;
    if (r < rcnt) {
        float4 acc = { scb[c0 * 4], scb[c0 * 4 + 1], scb[c0 * 4 + 2], scb[c0 * 4 + 3] };
#pragma unroll
        for (int k = 0; k < 3; ++k) {
            const float* tr = &tile[(r + k) * 36];
#pragma unroll
            for (int ci4 = 0; ci4 < 8; ++ci4) {
                float4 xv = *(const float4*)&tr[ci4 * 4];
#pragma unroll
                for (int q = 0; q < 4; ++q) {
                    int ci = ci4 * 4 + q;
                    float4 wv = *(const float4*)&scwT[(ci * 3 + k) * 16 + c0 * 4];
                    float xq = q == 0 ? xv.x : q == 1 ? xv.y : q == 2 ? xv.z : xv.w;
                    acc.x += xq * wv.x;
                    acc.y += xq * wv.y;
                    acc.z += xq * wv.z;
                    acc.w += xq * wv.w;
                }
            }
        }
        float4 yv;
        yv.x = acc.x > 0.f ? acc.x : 0.f;
        yv.y = acc.y > 0.f ? acc.y : 0.f;
        yv.z = acc.z > 0.f ? acc.z : 0.f;
        yv.w = acc.w > 0.f ? acc.w : 0.f;
        *(float4*)&ytile[r * 20 + c0 * 4] = yv;
    }
    __syncthreads();
    int items = rcnt * 22;
    for (int it = threadIdx.x; it < items; it += 256) {
        int row = it / 22, col = it - row * 22;
        const float* yr = &ytile[row * 20];
        const float* wc = &sfwT[col * 16];
        float s = sfb[col];
#pragma unroll
        for (int co4 = 0; co4 < 4; ++co4) {
            float4 yv = *(const float4*)&yr[co4 * 4];
            float4 wv = *(const float4*)&wc[co4 * 4];
            s += yv.x * wv.x + yv.y * wv.y + yv.z * wv.z + yv.w * wv.w;
        }
        out[(size_t)base * 22 + it] = s;
    }
}

extern "C" void kernel_launch(void* const* d_in, const int* in_sizes, int n_in,
                              void* d_out, int out_size, void* d_ws, size_t ws_size,
                              hipStream_t stream) {
    const float* x  = (const float*)d_in[0];
    const int*   ei = (const int*)d_in[1];   // int32 (JAX x64 disabled)
    const float* W1 = (const float*)d_in[2];
    const float* b1 = (const float*)d_in[3];
    const float* W2 = (const float*)d_in[4];
    const float* b2 = (const float*)d_in[5];
    const float* cw = (const float*)d_in[6];
    const float* cb = (const float*)d_in[7];
    const float* fw = (const float*)d_in[8];
    const float* fb = (const float*)d_in[9];
    float* out = (float*)d_out;

    int N = in_sizes[0] / 8;       // 100000
    int E = in_sizes[1] / 2;       // 3200000
    const int* src = ei;
    const int* dst = ei + E;
    int NB = (N + BKT_NODES - 1) >> BKT_SHIFT;  // 391

    auto alignB = [](size_t v) { return (v + 1023) & ~(size_t)1023; };
    char* wsb = (char*)d_ws;
    size_t o = 0;
    int* bcnt = (int*)(wsb + o);      o += 2048;
    int* boff = (int*)(wsb + o);      o += 2048;
    int* bcur = (int*)(wsb + o);      o += 2048;
    int* rowstart = (int*)(wsb + o);  o += alignB((size_t)(N + 1) * 4);
    float* dinv = (float*)(wsb + o);  o += alignB((size_t)N * 4);
    int* csr = (int*)(wsb + o);       o += alignB((size_t)E * 4 + 256);
    __half2* hx = (__half2*)(wsb + o);  o += alignB((size_t)N * 8 * 2);   // [N][8] fp16
    __half* hw2 = (__half*)(wsb + o);   o += alignB((size_t)N * 32 * 2);  // [N][32] fp16
    float* B = (float*)(wsb + o);     o += (size_t)N * 64 * 4;            // g2
    int* ebuf = (int*)B;              // dead before B's first write

    hipMemsetAsync(bcnt, 0, (size_t)NB * sizeof(int), stream);
    k_hist<<<(E + 4095) / 4096, 256, 0, stream>>>(dst, bcnt, E, NB);
    k_bscan<<<1, 512, 0, stream>>>(bcnt, boff, bcur, NB, E);
    k_part<<<(E + 8191) / 8192, 1024, 0, stream>>>(src, dst, bcur, ebuf, E, NB);
    k_lsort<<<NB, 256, 0, stream>>>(boff, ebuf, x, rowstart, dinv, hx, csr, N, NB);

    k_agg1g<<<(int)(((size_t)N * 4 + 255) / 256), 256, 0, stream>>>(rowstart, csr, dinv, hx, W1, b1, W2, hw2, N);

    k_aggr32p<<<(int)(((size_t)N * 16 + 255) / 256), 256, 0, stream>>>(rowstart, csr, dinv, hw2, b2, B, N);

    k_head<<<(N - 2 + HROWS - 1) / HROWS, 256, 0, stream>>>(B, cw, cb, fw, fb, out, N - 2);
}